// Round 9
// baseline (545.535 us; speedup 1.0000x reference)
//
#include <hip/hip_runtime.h>
#include <cstdint>
#include <cstddef>

#define TSEQ 4096
#define BATCH 2
#define DIM 256
#define NHEAD 8
#define HDIM 32
#define NLAYER 4
#define FFDIM 1024
#define SPLITN 2048
#define MROWS (BATCH * TSEQ)   // 8192

#define QSCALE 0.2550784545f   // (1/sqrt(HD)) * log2(e), folded into q

typedef __attribute__((ext_vector_type(4))) float f32x4;
typedef __attribute__((ext_vector_type(8))) short bf16x8;

__device__ __forceinline__ short f2bf(float f) {
  union { float f; uint32_t u; } v; v.f = f;
  uint32_t r = v.u + 0x7fffu + ((v.u >> 16) & 1u);
  return (short)(r >> 16);
}

__device__ __forceinline__ float bf2f(short s) {
  union { uint32_t u; float f; } v; v.u = ((uint32_t)(uint16_t)s) << 16;
  return v.f;
}

__device__ __forceinline__ float fast_exp2(float x) {
#if __has_builtin(__builtin_amdgcn_exp2f)
  return __builtin_amdgcn_exp2f(x);
#else
  float r;
  asm volatile("v_exp_f32 %0, %1\n\ts_nop 1" : "=v"(r) : "v"(x));
  return r;
#endif
}

__device__ __forceinline__ uint32_t pack2bf(float a, float b) {
  union { float f; uint32_t u; } ua, ub; ua.f = a; ub.f = b;
  return ((ua.u + 0x8000u) >> 16) | ((ub.u + 0x8000u) & 0xffff0000u);
}

__device__ __forceinline__ float gelu_f(float x) {
  float u = 0.7978845608f * x * (1.0f + 0.044715f * x * x);
  u = fminf(fmaxf(u, -20.f), 20.f);
  float e = fast_exp2(2.885390082f * u);   // exp(2u)
  float t = (e - 1.0f) / (e + 1.0f);
  return 0.5f * x * (1.0f + t);
}

#define AS1 __attribute__((address_space(1)))
#define AS3 __attribute__((address_space(3)))
__device__ __forceinline__ void gload16(const void* g, void* l) {
  __builtin_amdgcn_global_load_lds((AS1 void*)g, (AS3 void*)l, 16, 0, 0);
}

// ---------------------------------------------------------------- weight prep
__global__ __launch_bounds__(256) void prep_w(
    const float* __restrict__ Wq, const float* __restrict__ Wk,
    const float* __restrict__ Wv, const float* __restrict__ Wo,
    const float* __restrict__ W1, const float* __restrict__ W2,
    short* __restrict__ qkvT, short* __restrict__ woT,
    short* __restrict__ w1T, short* __restrict__ w2T)
{
  const int NQKV = NLAYER * 768 * DIM;
  const int NO   = NLAYER * DIM * DIM;
  const int NF   = NLAYER * FFDIM * DIM;
  const int total = NQKV + NO + 2 * NF;
  for (int idx = blockIdx.x * 256 + threadIdx.x; idx < total; idx += gridDim.x * 256) {
    if (idx < NQKV) {                       // qkvT[l][n:768][k:256]
      const int l = idx / (768 * DIM);
      const int rem = idx - l * 768 * DIM;
      const int n = rem >> 8, k = rem & 255;
      const float* src = (n < 256) ? Wq : ((n < 512) ? Wk : Wv);
      qkvT[idx] = f2bf(src[((size_t)l * DIM + k) * DIM + (n & 255)]);
    } else if (idx < NQKV + NO) {           // woT[l][n:256][k:256]
      const int j = idx - NQKV;
      const int l = j >> 16;
      const int rem = j & 65535;
      const int n = rem >> 8, k = rem & 255;
      woT[j] = f2bf(Wo[((size_t)l * DIM + k) * DIM + n]);
    } else if (idx < NQKV + NO + NF) {      // w1T[l][n:1024][k:256]
      const int j = idx - NQKV - NO;
      const int l = j >> 18;
      const int rem = j & 262143;
      const int n = rem >> 8, k = rem & 255;
      w1T[j] = f2bf(W1[((size_t)l * DIM + k) * FFDIM + n]);
    } else {                                // w2T[l][n:256][k:1024]
      const int j = idx - NQKV - NO - NF;
      const int l = j >> 18;
      const int rem = j & 262143;
      const int n = rem >> 10, k = rem & 1023;
      w2T[j] = f2bf(W2[((size_t)l * FFDIM + k) * DIM + n]);
    }
  }
}

// ------------------------------------------------------------------- x prep
__global__ __launch_bounds__(256) void prep_x(
    const float* __restrict__ rows, const float* __restrict__ tte,
    float* __restrict__ xf, short* __restrict__ xb)
{
  const size_t idx = (size_t)blockIdx.x * 256 + threadIdx.x;  // float4 index
  float4 v = ((const float4*)rows)[idx];
  const size_t e = idx * 4;
  const int m = (int)(e >> 8);
  const int d = (int)(e & 255);
  const int t = m & (TSEQ - 1);
  const int bb = m >> 12;
  if (t < SPLITN) {
    const float4 a = ((const float4*)tte)[((size_t)bb * SPLITN + t) * (DIM / 4) + (d >> 2)];
    v.x += a.x; v.y += a.y; v.z += a.z; v.w += a.w;
  }
  ((float4*)xf)[idx] = v;
  short4 pk; pk.x = f2bf(v.x); pk.y = f2bf(v.y); pk.z = f2bf(v.z); pk.w = f2bf(v.w);
  ((short4*)xb)[idx] = pk;
}

// ------------------------------------------------------------------ QKV GEMM
// 128x128 tile, K=256, 4 waves 2x2 (wave tile 64x64).  Epilogue: +bias,
// q-scale, bf16 out.
__global__ __launch_bounds__(256, 2) void qkv_gemm(
    const short* __restrict__ A, const short* __restrict__ BT,
    const float* __restrict__ bq, const float* __restrict__ bk,
    const float* __restrict__ bv, short* __restrict__ Cout)
{
  __shared__ short As[128 * 64];
  __shared__ short Bs[128 * 64];
  const int tid = threadIdx.x;
  const int lane = tid & 63;
  const int wave = tid >> 6;
  const int wm = wave & 1, wn = wave >> 1;
  const int col = lane & 15, quad = lane >> 4;

  const short* Ab = A + (size_t)blockIdx.x * 128 * DIM;
  const short* Bb = BT + (size_t)blockIdx.y * 128 * DIM;

  const f32x4 fz = {0.f, 0.f, 0.f, 0.f};
  f32x4 acc[4][4];
#pragma unroll
  for (int i = 0; i < 4; ++i)
#pragma unroll
    for (int j = 0; j < 4; ++j) acc[i][j] = fz;

  for (int k0 = 0; k0 < DIM; k0 += 64) {
#pragma unroll
    for (int p = 0; p < 4; ++p) {
      int i = p * 256 + tid;
      gload16(Ab + (size_t)(i >> 3) * DIM + k0 + (i & 7) * 8, &As[i * 8]);
      gload16(Bb + (size_t)(i >> 3) * DIM + k0 + (i & 7) * 8, &Bs[i * 8]);
    }
    __syncthreads();
#pragma unroll
    for (int ks = 0; ks < 64; ks += 32) {
      bf16x8 af[4], bf[4];
#pragma unroll
      for (int tm = 0; tm < 4; ++tm)
        af[tm] = *(const bf16x8*)&As[(wm * 64 + tm * 16 + col) * 64 + ks + quad * 8];
#pragma unroll
      for (int tn = 0; tn < 4; ++tn)
        bf[tn] = *(const bf16x8*)&Bs[(wn * 64 + tn * 16 + col) * 64 + ks + quad * 8];
#pragma unroll
      for (int tm = 0; tm < 4; ++tm)
#pragma unroll
        for (int tn = 0; tn < 4; ++tn)
          acc[tm][tn] = __builtin_amdgcn_mfma_f32_16x16x32_bf16(af[tm], bf[tn], acc[tm][tn], 0, 0, 0);
    }
    __syncthreads();
  }

#pragma unroll
  for (int tm = 0; tm < 4; ++tm) {
    const int mbase = blockIdx.x * 128 + wm * 64 + tm * 16 + quad * 4;
#pragma unroll
    for (int tn = 0; tn < 4; ++tn) {
      const int n = blockIdx.y * 128 + wn * 64 + tn * 16 + col;
      const float bvv = (n < 256) ? bq[n] : ((n < 512) ? bk[n - 256] : bv[n - 512]);
      const float sc = (n < 256) ? QSCALE : 1.0f;
#pragma unroll
      for (int r = 0; r < 4; ++r)
        Cout[(size_t)(mbase + r) * 768 + n] = f2bf((acc[tm][tn][r] + bvv) * sc);
    }
  }
}

// ------------------------------------------------ Wo GEMM + residual + LN1
// A staged from Opart (2 key-halves, fp32) + lpart (combine+normalize+pack
// fused into staging).  M-tile 32, N=256 full, K=256.
__global__ __launch_bounds__(256, 3) void wo_ln(
    const float* __restrict__ Opart, const float* __restrict__ lpart,
    const short* __restrict__ BT, const float* __restrict__ bias,
    const float* __restrict__ xres,
    const float* __restrict__ gs, const float* __restrict__ gb,
    float* __restrict__ xoutf, short* __restrict__ xoutb)
{
  __shared__ short As[32 * 64];
  __shared__ short Bs[256 * 64];
  __shared__ float ssum[4][32], ssq[4][32];
  const int tid = threadIdx.x;
  const int lane = tid & 63;
  const int wave = tid >> 6;
  const int col = lane & 15, quad = lane >> 4;
  const int m0 = blockIdx.x * 32;

  const f32x4 fz = {0.f, 0.f, 0.f, 0.f};
  f32x4 acc[2][4];
#pragma unroll
  for (int i = 0; i < 2; ++i)
#pragma unroll
    for (int j = 0; j < 4; ++j) acc[i][j] = fz;

  const int arow = tid >> 3;
  const int agr  = tid & 7;
  const int grow = m0 + arow;
  const int tt = grow & (TSEQ - 1), bb = grow >> 12;

  for (int k0 = 0; k0 < DIM; k0 += 64) {
    {
      const int head = (k0 >> 5) + (agr >= 4 ? 1 : 0);
      const size_t lidx = (size_t)(bb * 8 + head) * TSEQ + tt;
      const float l = lpart[lidx] + lpart[(size_t)16 * TSEQ + lidx];
      const float li = 1.0f / l;
      const size_t obase = (size_t)grow * DIM + k0 + agr * 8;
      const float4 a0 = *(const float4*)(Opart + obase);
      const float4 a1 = *(const float4*)(Opart + obase + 4);
      const float4 c0 = *(const float4*)(Opart + (size_t)MROWS * DIM + obase);
      const float4 c1 = *(const float4*)(Opart + (size_t)MROWS * DIM + obase + 4);
      uint4 w;
      w.x = pack2bf((a0.x + c0.x) * li, (a0.y + c0.y) * li);
      w.y = pack2bf((a0.z + c0.z) * li, (a0.w + c0.w) * li);
      w.z = pack2bf((a1.x + c1.x) * li, (a1.y + c1.y) * li);
      w.w = pack2bf((a1.z + c1.z) * li, (a1.w + c1.w) * li);
      *(uint4*)&As[arow * 64 + ((agr ^ (arow & 7)) * 8)] = w;
    }
#pragma unroll
    for (int p = 0; p < 8; ++p) {
      int i = p * 256 + tid;
      gload16(BT + (size_t)(i >> 3) * DIM + k0 + (i & 7) * 8, &Bs[i * 8]);
    }
    __syncthreads();
#pragma unroll
    for (int ks = 0; ks < 64; ks += 32) {
      bf16x8 af[2], bfr[4];
#pragma unroll
      for (int tm = 0; tm < 2; ++tm) {
        const int row = tm * 16 + col;
        const int g = (ks >> 3) + quad;
        af[tm] = *(const bf16x8*)&As[row * 64 + ((g ^ (row & 7)) * 8)];
      }
#pragma unroll
      for (int tn = 0; tn < 4; ++tn)
        bfr[tn] = *(const bf16x8*)&Bs[(wave * 64 + tn * 16 + col) * 64 + ks + quad * 8];
#pragma unroll
      for (int tm = 0; tm < 2; ++tm)
#pragma unroll
        for (int tn = 0; tn < 4; ++tn)
          acc[tm][tn] = __builtin_amdgcn_mfma_f32_16x16x32_bf16(af[tm], bfr[tn], acc[tm][tn], 0, 0, 0);
    }
    __syncthreads();
  }

  const float* resb = xres + (size_t)m0 * DIM;
#pragma unroll
  for (int tn = 0; tn < 4; ++tn) {
    const int n = wave * 64 + tn * 16 + col;
    const float bv = bias[n];
#pragma unroll
    for (int tm = 0; tm < 2; ++tm)
#pragma unroll
      for (int r = 0; r < 4; ++r) {
        const int row = tm * 16 + quad * 4 + r;
        acc[tm][tn][r] += bv + resb[(size_t)row * DIM + n];
      }
  }

#pragma unroll
  for (int tm = 0; tm < 2; ++tm)
#pragma unroll
    for (int r = 0; r < 4; ++r) {
      float s = 0.f, q = 0.f;
#pragma unroll
      for (int tn = 0; tn < 4; ++tn) { const float v = acc[tm][tn][r]; s += v; q += v * v; }
      s += __shfl_xor(s, 1); q += __shfl_xor(q, 1);
      s += __shfl_xor(s, 2); q += __shfl_xor(q, 2);
      s += __shfl_xor(s, 4); q += __shfl_xor(q, 4);
      s += __shfl_xor(s, 8); q += __shfl_xor(q, 8);
      if (col == 0) { const int row = tm * 16 + quad * 4 + r; ssum[wave][row] = s; ssq[wave][row] = q; }
    }
  __syncthreads();
  if (tid < 32) {
    const float S = ssum[0][tid] + ssum[1][tid] + ssum[2][tid] + ssum[3][tid];
    const float Q = ssq[0][tid] + ssq[1][tid] + ssq[2][tid] + ssq[3][tid];
    const float mu = S * (1.0f / DIM);
    const float var = Q * (1.0f / DIM) - mu * mu;
    ssum[0][tid] = mu;
    ssq[0][tid] = rsqrtf(var + 1e-5f);
  }
  __syncthreads();

#pragma unroll
  for (int tm = 0; tm < 2; ++tm)
#pragma unroll
    for (int tn = 0; tn < 4; ++tn) {
      const int n = wave * 64 + tn * 16 + col;
      const float g = gs[n], bb2 = gb[n];
#pragma unroll
      for (int r = 0; r < 4; ++r) {
        const int row = tm * 16 + quad * 4 + r;
        const float out = (acc[tm][tn][r] - ssum[0][row]) * ssq[0][row] * g + bb2;
        xoutf[(size_t)(m0 + row) * DIM + n] = out;
        xoutb[(size_t)(m0 + row) * DIM + n] = f2bf(out);
      }
    }
}

// ------------------------------------------------ FF fused: gelu(x@W1+b1)@W2
// + b2 + residual + LN2.  M-tile 32, grid 256 = 1 block/CU.  h in LDS
// (row-major, stride 1032 -> conflict-free b128 A-frags).  W1/W2 streamed
// via double-buffered 32KB DMA tiles.  x A-frags held in registers.
#define HP 1032

__global__ __launch_bounds__(256, 1) void ff_fused(
    const short* __restrict__ xbA, const short* __restrict__ w1T,
    const float* __restrict__ b1, const short* __restrict__ w2T,
    const float* __restrict__ b2, const float* __restrict__ xres,
    const float* __restrict__ gs, const float* __restrict__ gb,
    float* __restrict__ xoutf, short* __restrict__ xoutb)
{
  __shared__ short As[32 * 256];        // 16 KB
  __shared__ short Wb[2][64 * 256];     // 2 x 32 KB (ff2 views as [256][64])
  __shared__ short Hs[32 * HP];         // 64.5 KB
  __shared__ float ssum[4][32], ssq[4][32];

  const int tid = threadIdx.x;
  const int lane = tid & 63;
  const int wave = tid >> 6;
  const int col = lane & 15, quad = lane >> 4;
  const int m0 = blockIdx.x * 32;

  // stage A (32x256) + W1 tile 0
#pragma unroll
  for (int p = 0; p < 4; ++p) {
    int i = p * 256 + tid;
    gload16(xbA + (size_t)(m0 + (i >> 5)) * DIM + (i & 31) * 8, &As[i * 8]);
  }
#pragma unroll
  for (int p = 0; p < 8; ++p) {
    int i = p * 256 + tid;
    gload16(w1T + (size_t)(i >> 5) * DIM + (i & 31) * 8, &Wb[0][i * 8]);
  }

  const f32x4 fz = {0.f, 0.f, 0.f, 0.f};
  bf16x8 af1[2][8];

  // ---------------- ff1: h = gelu(x @ W1 + b1), written to Hs
  for (int nt = 0; nt < 16; ++nt) {
    __syncthreads();
    if (nt + 1 < 16) {
#pragma unroll
      for (int p = 0; p < 8; ++p) {
        int i = p * 256 + tid;
        gload16(w1T + (size_t)((nt + 1) * 64 + (i >> 5)) * DIM + (i & 31) * 8,
                &Wb[(nt + 1) & 1][i * 8]);
      }
    }
    if (nt == 0) {
#pragma unroll
      for (int tm = 0; tm < 2; ++tm)
#pragma unroll
        for (int kf = 0; kf < 8; ++kf)
          af1[tm][kf] = *(const bf16x8*)&As[(tm * 16 + col) * 256 + kf * 32 + quad * 8];
    }
    const short* wb = Wb[nt & 1];
    f32x4 a0 = fz, a1 = fz;
#pragma unroll
    for (int kf = 0; kf < 8; ++kf) {
      const bf16x8 bfv = *(const bf16x8*)&wb[(wave * 16 + col) * 256 + kf * 32 + quad * 8];
      a0 = __builtin_amdgcn_mfma_f32_16x16x32_bf16(af1[0][kf], bfv, a0, 0, 0, 0);
      a1 = __builtin_amdgcn_mfma_f32_16x16x32_bf16(af1[1][kf], bfv, a1, 0, 0, 0);
    }
    const int n = nt * 64 + wave * 16 + col;
    const float bv = b1[n];
#pragma unroll
    for (int r = 0; r < 4; ++r) {
      Hs[(quad * 4 + r) * HP + n]        = f2bf(gelu_f(a0[r] + bv));
      Hs[(16 + quad * 4 + r) * HP + n]   = f2bf(gelu_f(a1[r] + bv));
    }
  }
  __syncthreads();   // h complete; all W1 reads done

  // stage W2 tile 0
#pragma unroll
  for (int p = 0; p < 8; ++p) {
    int i = p * 256 + tid;
    gload16(w2T + (size_t)(i >> 3) * FFDIM + (i & 7) * 8, &Wb[0][i * 8]);
  }

  // ---------------- ff2: acc = h @ W2
  f32x4 acc[2][4];
#pragma unroll
  for (int i = 0; i < 2; ++i)
#pragma unroll
    for (int j = 0; j < 4; ++j) acc[i][j] = fz;

  for (int kt = 0; kt < 16; ++kt) {
    __syncthreads();
    if (kt + 1 < 16) {
#pragma unroll
      for (int p = 0; p < 8; ++p) {
        int i = p * 256 + tid;
        gload16(w2T + (size_t)(i >> 3) * FFDIM + (kt + 1) * 64 + (i & 7) * 8,
                &Wb[(kt + 1) & 1][i * 8]);
      }
    }
    const short* wb = Wb[kt & 1];
#pragma unroll
    for (int ks = 0; ks < 2; ++ks) {
      bf16x8 af[2], bfr[4];
#pragma unroll
      for (int tm = 0; tm < 2; ++tm)
        af[tm] = *(const bf16x8*)&Hs[(tm * 16 + col) * HP + kt * 64 + ks * 32 + quad * 8];
#pragma unroll
      for (int tn = 0; tn < 4; ++tn)
        bfr[tn] = *(const bf16x8*)&wb[(wave * 64 + tn * 16 + col) * 64 + ks * 32 + quad * 8];
#pragma unroll
      for (int tm = 0; tm < 2; ++tm)
#pragma unroll
        for (int tn = 0; tn < 4; ++tn)
          acc[tm][tn] = __builtin_amdgcn_mfma_f32_16x16x32_bf16(af[tm], bfr[tn], acc[tm][tn], 0, 0, 0);
    }
  }

  // ---------------- epilogue: bias + residual + LN2
  const float* resb = xres + (size_t)m0 * DIM;
#pragma unroll
  for (int tn = 0; tn < 4; ++tn) {
    const int n = wave * 64 + tn * 16 + col;
    const float bv = b2[n];
#pragma unroll
    for (int tm = 0; tm < 2; ++tm)
#pragma unroll
      for (int r = 0; r < 4; ++r) {
        const int row = tm * 16 + quad * 4 + r;
        acc[tm][tn][r] += bv + resb[(size_t)row * DIM + n];
      }
  }
#pragma unroll
  for (int tm = 0; tm < 2; ++tm)
#pragma unroll
    for (int r = 0; r < 4; ++r) {
      float s = 0.f, q = 0.f;
#pragma unroll
      for (int tn = 0; tn < 4; ++tn) { const float v = acc[tm][tn][r]; s += v; q += v * v; }
      s += __shfl_xor(s, 1); q += __shfl_xor(q, 1);
      s += __shfl_xor(s, 2); q += __shfl_xor(q, 2);
      s += __shfl_xor(s, 4); q += __shfl_xor(q, 4);
      s += __shfl_xor(s, 8); q += __shfl_xor(q, 8);
      if (col == 0) { const int row = tm * 16 + quad * 4 + r; ssum[wave][row] = s; ssq[wave][row] = q; }
    }
  __syncthreads();
  if (tid < 32) {
    const float S = ssum[0][tid] + ssum[1][tid] + ssum[2][tid] + ssum[3][tid];
    const float Q = ssq[0][tid] + ssq[1][tid] + ssq[2][tid] + ssq[3][tid];
    const float mu = S * (1.0f / DIM);
    const float var = Q * (1.0f / DIM) - mu * mu;
    ssum[0][tid] = mu;
    ssq[0][tid] = rsqrtf(var + 1e-5f);
  }
  __syncthreads();
#pragma unroll
  for (int tm = 0; tm < 2; ++tm)
#pragma unroll
    for (int tn = 0; tn < 4; ++tn) {
      const int n = wave * 64 + tn * 16 + col;
      const float g = gs[n], bb2 = gb[n];
#pragma unroll
      for (int r = 0; r < 4; ++r) {
        const int row = tm * 16 + quad * 4 + r;
        const float out = (acc[tm][tn][r] - ssum[0][row]) * ssq[0][row] * g + bb2;
        xoutf[(size_t)(m0 + row) * DIM + n] = out;
        xoutb[(size_t)(m0 + row) * DIM + n] = f2bf(out);
      }
    }
}

// ----------------------------------------------------------------- attention
// Key-split x2 (blockIdx.z).  Block = 128 queries of one (b,h); 4 waves x 32q.
// K staged via DMA in hd-part planes [part][key].  V staged from qkv as
// key-PAIRS: threads 0..127 load 2 keys x 8hd and write 8 ds_write_b32 into
// the swizzled [hd][key] plane (half the LDS insts of b16 staging).
#define AKT 64
#define KSPL 1024
#define NKT (KSPL / AKT)

__global__ __launch_bounds__(256, 4) void attn_kernel(
    const short* __restrict__ qkv,
    float* __restrict__ Opart, float* __restrict__ lpart)
{
  __shared__ short Kbuf[2][AKT * HDIM];   // [part(4)][key(64)][8]
  __shared__ short Vbuf[2][HDIM * AKT];   // [hd][key-swz]
  __shared__ short Pall[4][32][72];
  __shared__ float Pdiag[4][16];

  const int tid = threadIdx.x;
  const int lane = tid & 63;
  const int wave = tid >> 6;
  const int col = lane & 15, quad = lane >> 4;
  const int bh = blockIdx.y;
  const int b = bh >> 3, h = bh & 7;
  const int hz = blockIdx.z;
  const int q0 = blockIdx.x * 128 + wave * 32;

  short (*P)[72] = Pall[wave];

  const short* qbase = qkv + (size_t)b * TSEQ * 768 + h * HDIM;
  const short* kbase = qbase + 256;
  const short* vcol  = qbase + 512;

  const short* ksrc = kbase + (size_t)(hz * KSPL + (tid & 63)) * 768 + (tid >> 6) * 8;

  // V pair staging (threads 0..127): hg = tid>>5, pair = tid&31 -> keys 2p,2p+1
  const int vhg = (tid & 127) >> 5, vpr = tid & 31;
  const int vva = vpr >> 2, vb8 = (vpr & 3) * 2;
  const short* vsrc = vcol + (size_t)(hz * KSPL + 2 * vpr) * 768 + vhg * 8;
  const bool vact = (tid < 128);

  const bf16x8 qf0 = *(const bf16x8*)(qbase + (size_t)(q0 + col) * 768 + quad * 8);
  const bf16x8 qf1 = *(const bf16x8*)(qbase + (size_t)(q0 + 16 + col) * 768 + quad * 8);

  bf16x8 ones;
#pragma unroll
  for (int i = 0; i < 8; ++i) ones[i] = (short)0x3F80;

  const f32x4 fz = {0.f, 0.f, 0.f, 0.f};
  f32x4 o[2][2] = {{fz, fz}, {fz, fz}};
  f32x4 lacc[2] = {fz, fz};

  // prologue
  gload16(ksrc, &Kbuf[0][tid * 8]);
  bf16x8 vn0, vn1;
  if (vact) {
    const bf16x8 v0 = *(const bf16x8*)vsrc;
    const bf16x8 v1 = *(const bf16x8*)(vsrc + 768);
#pragma unroll
    for (int j = 0; j < 8; ++j) {
      const uint32_t w = (uint32_t)(uint16_t)v0[j] | ((uint32_t)(uint16_t)v1[j] << 16);
      *(uint32_t*)&Vbuf[0][(vhg * 8 + j) * 64 + ((vva ^ j) * 8) + vb8] = w;
    }
    vn0 = *(const bf16x8*)(vsrc + (size_t)AKT * 768);
    vn1 = *(const bf16x8*)(vsrc + (size_t)AKT * 768 + 768);
  }

  int cur = 0;
  for (int t = 0; t < NKT; ++t) {
    __syncthreads();
    if (t + 1 < NKT) {
      gload16(ksrc + (size_t)(t + 1) * AKT * 768, &Kbuf[1 - cur][tid * 8]);
      if (vact) {
#pragma unroll
        for (int j = 0; j < 8; ++j) {
          const uint32_t w = (uint32_t)(uint16_t)vn0[j] | ((uint32_t)(uint16_t)vn1[j] << 16);
          *(uint32_t*)&Vbuf[1 - cur][(vhg * 8 + j) * 64 + ((vva ^ j) * 8) + vb8] = w;
        }
        if (t + 2 < NKT) {
          vn0 = *(const bf16x8*)(vsrc + (size_t)(t + 2) * AKT * 768);
          vn1 = *(const bf16x8*)(vsrc + (size_t)(t + 2) * AKT * 768 + 768);
        }
      }
    }
    const short* kb = Kbuf[cur];
    const short* vb = Vbuf[cur];

    // ---- S phase
#pragma unroll
    for (int st = 0; st < 4; ++st) {
      const bf16x8 kf = *(const bf16x8*)&kb[(quad * 64 + st * 16 + col) * 8];
      const f32x4 s0 = __builtin_amdgcn_mfma_f32_16x16x32_bf16(kf, qf0, fz, 0, 0, 0);
      const f32x4 s1 = __builtin_amdgcn_mfma_f32_16x16x32_bf16(kf, qf1, fz, 0, 0, 0);
      uint2 w0, w1;
      w0.x = pack2bf(fast_exp2(s0[0]), fast_exp2(s0[1]));
      w0.y = pack2bf(fast_exp2(s0[2]), fast_exp2(s0[3]));
      w1.x = pack2bf(fast_exp2(s1[0]), fast_exp2(s1[1]));
      w1.y = pack2bf(fast_exp2(s1[2]), fast_exp2(s1[3]));
      *(uint2*)&P[col][st * 16 + quad * 4] = w0;
      *(uint2*)&P[16 + col][st * 16 + quad * 4] = w1;
    }
    asm volatile("s_waitcnt lgkmcnt(0)" ::: "memory");

    // ---- PV phase
#pragma unroll
    for (int kh = 0; kh < 2; ++kh) {
      const bf16x8 pf0 = *(const bf16x8*)&P[col][kh * 32 + quad * 8];
      const bf16x8 pf1 = *(const bf16x8*)&P[16 + col][kh * 32 + quad * 8];
#pragma unroll
      for (int hh = 0; hh < 2; ++hh) {
        const int hd = hh * 16 + col;
        const bf16x8 vf = *(const bf16x8*)&vb[hd * AKT + (((kh * 4 + quad) ^ (hd & 7)) * 8)];
        o[0][hh] = __builtin_amdgcn_mfma_f32_16x16x32_bf16(pf0, vf, o[0][hh], 0, 0, 0);
        o[1][hh] = __builtin_amdgcn_mfma_f32_16x16x32_bf16(pf1, vf, o[1][hh], 0, 0, 0);
      }
      lacc[0] = __builtin_amdgcn_mfma_f32_16x16x32_bf16(pf0, ones, lacc[0], 0, 0, 0);
      lacc[1] = __builtin_amdgcn_mfma_f32_16x16x32_bf16(pf1, ones, lacc[1], 0, 0, 0);
    }
    cur ^= 1;
  }

  // ---- diagonal self-key (elementwise) for test-query blocks
  if (hz == 1 && blockIdx.x >= SPLITN / 128) {
#pragma unroll
    for (int qsub = 0; qsub < 2; ++qsub) {
      const int qd = q0 + qsub * 16;
      const bf16x8 qf = qsub ? qf1 : qf0;
      const bf16x8 kf = *(const bf16x8*)(kbase + (size_t)(qd + col) * 768 + quad * 8);
      const f32x4 sd = __builtin_amdgcn_mfma_f32_16x16x32_bf16(kf, qf, fz, 0, 0, 0);
      float ps = 0.f;
#pragma unroll
      for (int r = 0; r < 4; ++r)
        if (quad * 4 + r == col) ps = fast_exp2(sd[r]);
      if (quad == (col >> 2)) Pdiag[wave][col] = ps;
      asm volatile("s_waitcnt lgkmcnt(0)" ::: "memory");
      const f32x4 pv = *(const f32x4*)&Pdiag[wave][quad * 4];
#pragma unroll
      for (int r = 0; r < 4; ++r) {
        lacc[qsub][r] += pv[r];
        const size_t vrow = (size_t)(qd + quad * 4 + r) * 768;
#pragma unroll
        for (int hh = 0; hh < 2; ++hh)
          o[qsub][hh][r] += pv[r] * bf2f(vcol[vrow + hh * 16 + col]);
      }
      asm volatile("s_waitcnt lgkmcnt(0)" ::: "memory");
    }
  }

  // ---- partial epilogue
  float* Ob = Opart + (size_t)hz * MROWS * DIM;
  float* lb = lpart + (size_t)hz * 16 * TSEQ + (size_t)bh * TSEQ;
#pragma unroll
  for (int qsub = 0; qsub < 2; ++qsub) {
    const f32x4 la = lacc[qsub];
    const int qq = q0 + qsub * 16 + quad * 4;
    const int rowb = b * TSEQ + qq;
#pragma unroll
    for (int r = 0; r < 4; ++r) {
      if (col == 0) lb[qq + r] = la[r];
#pragma unroll
      for (int hh = 0; hh < 2; ++hh)
        Ob[(size_t)(rowb + r) * DIM + h * HDIM + hh * 16 + col] = o[qsub][hh][r];
    }
  }
}

// ------------------------------------------------------------------ launch
extern "C" void kernel_launch(void* const* d_in, const int* in_sizes, int n_in,
                              void* d_out, int out_size, void* d_ws, size_t ws_size,
                              hipStream_t stream)
{
  const float* rows = (const float*)d_in[0];
  const float* tte  = (const float*)d_in[1];
  const float* Wq = (const float*)d_in[2];  const float* bq = (const float*)d_in[3];
  const float* Wk = (const float*)d_in[4];  const float* bk = (const float*)d_in[5];
  const float* Wv = (const float*)d_in[6];  const float* bv = (const float*)d_in[7];
  const float* Wo = (const float*)d_in[8];  const float* bo = (const float*)d_in[9];
  const float* W1 = (const float*)d_in[10]; const float* b1 = (const float*)d_in[11];
  const float* W2 = (const float*)d_in[12]; const float* b2 = (const float*)d_in[13];
  const float* ln1s = (const float*)d_in[14]; const float* ln1b = (const float*)d_in[15];
  const float* ln2s = (const float*)d_in[16]; const float* ln2b = (const float*)d_in[17];

  char* p = (char*)d_ws;
  float* xf   = (float*)p;  p += (size_t)MROWS * DIM * 4;
  short* xb   = (short*)p;  p += (size_t)MROWS * DIM * 2;
  short* qkv  = (short*)p;  p += (size_t)MROWS * 768 * 2;
  float* Opart = (float*)p; p += (size_t)2 * MROWS * DIM * 4;
  float* lpart = (float*)p; p += (size_t)2 * 16 * TSEQ * 4;
  short* qkvT = (short*)p;  p += (size_t)NLAYER * 768 * DIM * 2;
  short* woT  = (short*)p;  p += (size_t)NLAYER * DIM * DIM * 2;
  short* w1T  = (short*)p;  p += (size_t)NLAYER * FFDIM * DIM * 2;
  short* w2T  = (short*)p;  p += (size_t)NLAYER * DIM * FFDIM * 2;

  prep_w<<<2048, 256, 0, stream>>>(Wq, Wk, Wv, Wo, W1, W2, qkvT, woT, w1T, w2T);
  prep_x<<<MROWS * DIM / 4 / 256, 256, 0, stream>>>(rows, tte, xf, xb);

  for (int l = 0; l < NLAYER; ++l) {
    qkv_gemm<<<dim3(MROWS / 128, 6), 256, 0, stream>>>(
        xb, qkvT + (size_t)l * 768 * DIM, bq + l * DIM, bk + l * DIM, bv + l * DIM, qkv);
    attn_kernel<<<dim3(TSEQ / 128, BATCH * NHEAD, 2), 256, 0, stream>>>(qkv, Opart, lpart);
    wo_ln<<<MROWS / 32, 256, 0, stream>>>(
        Opart, lpart, woT + (size_t)l * DIM * DIM, bo + l * DIM, xf,
        ln1s + l * DIM, ln1b + l * DIM, xf, xb);
    float* xo = (l == NLAYER - 1) ? (float*)d_out : xf;
    ff_fused<<<MROWS / 32, 256, 0, stream>>>(
        xb, w1T + (size_t)l * FFDIM * DIM, b1 + l * FFDIM,
        w2T + (size_t)l * DIM * FFDIM, b2 + l * DIM, xf,
        ln2s + l * DIM, ln2b + l * DIM, xo, xb);
  }
}

// Round 10
// 525.646 us; speedup vs baseline: 1.0378x; 1.0378x over previous
//
#include <hip/hip_runtime.h>
#include <cstdint>
#include <cstddef>

#define TSEQ 4096
#define BATCH 2
#define DIM 256
#define NHEAD 8
#define HDIM 32
#define NLAYER 4
#define FFDIM 1024
#define SPLITN 2048
#define MROWS (BATCH * TSEQ)   // 8192

#define QSCALE 0.2550784545f   // (1/sqrt(HD)) * log2(e), folded into q

typedef __attribute__((ext_vector_type(4))) float f32x4;
typedef __attribute__((ext_vector_type(8))) short bf16x8;

__device__ __forceinline__ short f2bf(float f) {
  union { float f; uint32_t u; } v; v.f = f;
  uint32_t r = v.u + 0x7fffu + ((v.u >> 16) & 1u);
  return (short)(r >> 16);
}

__device__ __forceinline__ float bf2f(short s) {
  union { uint32_t u; float f; } v; v.u = ((uint32_t)(uint16_t)s) << 16;
  return v.f;
}

__device__ __forceinline__ float fast_exp2(float x) {
#if __has_builtin(__builtin_amdgcn_exp2f)
  return __builtin_amdgcn_exp2f(x);
#else
  float r;
  asm volatile("v_exp_f32 %0, %1\n\ts_nop 1" : "=v"(r) : "v"(x));
  return r;
#endif
}

__device__ __forceinline__ uint32_t pack2bf(float a, float b) {
  union { float f; uint32_t u; } ua, ub; ua.f = a; ub.f = b;
  return ((ua.u + 0x8000u) >> 16) | ((ub.u + 0x8000u) & 0xffff0000u);
}

__device__ __forceinline__ float gelu_f(float x) {
  float u = 0.7978845608f * x * (1.0f + 0.044715f * x * x);
  u = fminf(fmaxf(u, -20.f), 20.f);
  float e = fast_exp2(2.885390082f * u);   // exp(2u)
  float t = (e - 1.0f) / (e + 1.0f);
  return 0.5f * x * (1.0f + t);
}

#define AS1 __attribute__((address_space(1)))
#define AS3 __attribute__((address_space(3)))
__device__ __forceinline__ void gload16(const void* g, void* l) {
  __builtin_amdgcn_global_load_lds((AS1 void*)g, (AS3 void*)l, 16, 0, 0);
}

// ---------------------------------------------------------------- weight prep
__global__ __launch_bounds__(256) void prep_w(
    const float* __restrict__ Wq, const float* __restrict__ Wk,
    const float* __restrict__ Wv, const float* __restrict__ Wo,
    const float* __restrict__ W1, const float* __restrict__ W2,
    short* __restrict__ qkvT, short* __restrict__ woT,
    short* __restrict__ w1T, short* __restrict__ w2T)
{
  const int NQKV = NLAYER * 768 * DIM;
  const int NO   = NLAYER * DIM * DIM;
  const int NF   = NLAYER * FFDIM * DIM;
  const int total = NQKV + NO + 2 * NF;
  for (int idx = blockIdx.x * 256 + threadIdx.x; idx < total; idx += gridDim.x * 256) {
    if (idx < NQKV) {                       // qkvT[l][n:768][k:256]
      const int l = idx / (768 * DIM);
      const int rem = idx - l * 768 * DIM;
      const int n = rem >> 8, k = rem & 255;
      const float* src = (n < 256) ? Wq : ((n < 512) ? Wk : Wv);
      qkvT[idx] = f2bf(src[((size_t)l * DIM + k) * DIM + (n & 255)]);
    } else if (idx < NQKV + NO) {           // woT[l][n:256][k:256]
      const int j = idx - NQKV;
      const int l = j >> 16;
      const int rem = j & 65535;
      const int n = rem >> 8, k = rem & 255;
      woT[j] = f2bf(Wo[((size_t)l * DIM + k) * DIM + n]);
    } else if (idx < NQKV + NO + NF) {      // w1T[l][n:1024][k:256]
      const int j = idx - NQKV - NO;
      const int l = j >> 18;
      const int rem = j & 262143;
      const int n = rem >> 8, k = rem & 255;
      w1T[j] = f2bf(W1[((size_t)l * DIM + k) * FFDIM + n]);
    } else {                                // w2T[l][n:256][k:1024]
      const int j = idx - NQKV - NO - NF;
      const int l = j >> 18;
      const int rem = j & 262143;
      const int n = rem >> 10, k = rem & 1023;
      w2T[j] = f2bf(W2[((size_t)l * FFDIM + k) * DIM + n]);
    }
  }
}

// ------------------------------------------------------------------- x prep
__global__ __launch_bounds__(256) void prep_x(
    const float* __restrict__ rows, const float* __restrict__ tte,
    float* __restrict__ xf, short* __restrict__ xb)
{
  const size_t idx = (size_t)blockIdx.x * 256 + threadIdx.x;  // float4 index
  float4 v = ((const float4*)rows)[idx];
  const size_t e = idx * 4;
  const int m = (int)(e >> 8);
  const int d = (int)(e & 255);
  const int t = m & (TSEQ - 1);
  const int bb = m >> 12;
  if (t < SPLITN) {
    const float4 a = ((const float4*)tte)[((size_t)bb * SPLITN + t) * (DIM / 4) + (d >> 2)];
    v.x += a.x; v.y += a.y; v.z += a.z; v.w += a.w;
  }
  ((float4*)xf)[idx] = v;
  short4 pk; pk.x = f2bf(v.x); pk.y = f2bf(v.y); pk.z = f2bf(v.z); pk.w = f2bf(v.w);
  ((short4*)xb)[idx] = pk;
}

// ------------------------------------------------------------------ QKV GEMM
// 128x128 tile, K=256, 4 waves 2x2.  Epilogue: +bias, q-scale, bf16 out.
__global__ __launch_bounds__(256, 2) void qkv_gemm(
    const short* __restrict__ A, const short* __restrict__ BT,
    const float* __restrict__ bq, const float* __restrict__ bk,
    const float* __restrict__ bv, short* __restrict__ Cout)
{
  __shared__ short As[128 * 64];
  __shared__ short Bs[128 * 64];
  const int tid = threadIdx.x;
  const int lane = tid & 63;
  const int wave = tid >> 6;
  const int wm = wave & 1, wn = wave >> 1;
  const int col = lane & 15, quad = lane >> 4;

  const short* Ab = A + (size_t)blockIdx.x * 128 * DIM;
  const short* Bb = BT + (size_t)blockIdx.y * 128 * DIM;

  const f32x4 fz = {0.f, 0.f, 0.f, 0.f};
  f32x4 acc[4][4];
#pragma unroll
  for (int i = 0; i < 4; ++i)
#pragma unroll
    for (int j = 0; j < 4; ++j) acc[i][j] = fz;

  for (int k0 = 0; k0 < DIM; k0 += 64) {
#pragma unroll
    for (int p = 0; p < 4; ++p) {
      int i = p * 256 + tid;
      gload16(Ab + (size_t)(i >> 3) * DIM + k0 + (i & 7) * 8, &As[i * 8]);
      gload16(Bb + (size_t)(i >> 3) * DIM + k0 + (i & 7) * 8, &Bs[i * 8]);
    }
    __syncthreads();
#pragma unroll
    for (int ks = 0; ks < 64; ks += 32) {
      bf16x8 af[4], bf[4];
#pragma unroll
      for (int tm = 0; tm < 4; ++tm)
        af[tm] = *(const bf16x8*)&As[(wm * 64 + tm * 16 + col) * 64 + ks + quad * 8];
#pragma unroll
      for (int tn = 0; tn < 4; ++tn)
        bf[tn] = *(const bf16x8*)&Bs[(wn * 64 + tn * 16 + col) * 64 + ks + quad * 8];
#pragma unroll
      for (int tm = 0; tm < 4; ++tm)
#pragma unroll
        for (int tn = 0; tn < 4; ++tn)
          acc[tm][tn] = __builtin_amdgcn_mfma_f32_16x16x32_bf16(af[tm], bf[tn], acc[tm][tn], 0, 0, 0);
    }
    __syncthreads();
  }

#pragma unroll
  for (int tm = 0; tm < 4; ++tm) {
    const int mbase = blockIdx.x * 128 + wm * 64 + tm * 16 + quad * 4;
#pragma unroll
    for (int tn = 0; tn < 4; ++tn) {
      const int n = blockIdx.y * 128 + wn * 64 + tn * 16 + col;
      const float bvv = (n < 256) ? bq[n] : ((n < 512) ? bk[n - 256] : bv[n - 512]);
      const float sc = (n < 256) ? QSCALE : 1.0f;
#pragma unroll
      for (int r = 0; r < 4; ++r)
        Cout[(size_t)(mbase + r) * 768 + n] = f2bf((acc[tm][tn][r] + bvv) * sc);
    }
  }
}

// ------------------------------------------------ Wo GEMM + residual + LN1
__global__ __launch_bounds__(256, 3) void wo_ln(
    const float* __restrict__ Opart, const float* __restrict__ lpart,
    const short* __restrict__ BT, const float* __restrict__ bias,
    const float* __restrict__ xres,
    const float* __restrict__ gs, const float* __restrict__ gb,
    float* __restrict__ xoutf, short* __restrict__ xoutb)
{
  __shared__ short As[32 * 64];
  __shared__ short Bs[256 * 64];
  __shared__ float ssum[4][32], ssq[4][32];
  const int tid = threadIdx.x;
  const int lane = tid & 63;
  const int wave = tid >> 6;
  const int col = lane & 15, quad = lane >> 4;
  const int m0 = blockIdx.x * 32;

  const f32x4 fz = {0.f, 0.f, 0.f, 0.f};
  f32x4 acc[2][4];
#pragma unroll
  for (int i = 0; i < 2; ++i)
#pragma unroll
    for (int j = 0; j < 4; ++j) acc[i][j] = fz;

  const int arow = tid >> 3;
  const int agr  = tid & 7;
  const int grow = m0 + arow;
  const int tt = grow & (TSEQ - 1), bb = grow >> 12;

  for (int k0 = 0; k0 < DIM; k0 += 64) {
    {
      const int head = (k0 >> 5) + (agr >= 4 ? 1 : 0);
      const size_t lidx = (size_t)(bb * 8 + head) * TSEQ + tt;
      const float l = lpart[lidx] + lpart[(size_t)16 * TSEQ + lidx];
      const float li = 1.0f / l;
      const size_t obase = (size_t)grow * DIM + k0 + agr * 8;
      const float4 a0 = *(const float4*)(Opart + obase);
      const float4 a1 = *(const float4*)(Opart + obase + 4);
      const float4 c0 = *(const float4*)(Opart + (size_t)MROWS * DIM + obase);
      const float4 c1 = *(const float4*)(Opart + (size_t)MROWS * DIM + obase + 4);
      uint4 w;
      w.x = pack2bf((a0.x + c0.x) * li, (a0.y + c0.y) * li);
      w.y = pack2bf((a0.z + c0.z) * li, (a0.w + c0.w) * li);
      w.z = pack2bf((a1.x + c1.x) * li, (a1.y + c1.y) * li);
      w.w = pack2bf((a1.z + c1.z) * li, (a1.w + c1.w) * li);
      *(uint4*)&As[arow * 64 + ((agr ^ (arow & 7)) * 8)] = w;
    }
#pragma unroll
    for (int p = 0; p < 8; ++p) {
      int i = p * 256 + tid;
      gload16(BT + (size_t)(i >> 3) * DIM + k0 + (i & 7) * 8, &Bs[i * 8]);
    }
    __syncthreads();
#pragma unroll
    for (int ks = 0; ks < 64; ks += 32) {
      bf16x8 af[2], bfr[4];
#pragma unroll
      for (int tm = 0; tm < 2; ++tm) {
        const int row = tm * 16 + col;
        const int g = (ks >> 3) + quad;
        af[tm] = *(const bf16x8*)&As[row * 64 + ((g ^ (row & 7)) * 8)];
      }
#pragma unroll
      for (int tn = 0; tn < 4; ++tn)
        bfr[tn] = *(const bf16x8*)&Bs[(wave * 64 + tn * 16 + col) * 64 + ks + quad * 8];
#pragma unroll
      for (int tm = 0; tm < 2; ++tm)
#pragma unroll
        for (int tn = 0; tn < 4; ++tn)
          acc[tm][tn] = __builtin_amdgcn_mfma_f32_16x16x32_bf16(af[tm], bfr[tn], acc[tm][tn], 0, 0, 0);
    }
    __syncthreads();
  }

  const float* resb = xres + (size_t)m0 * DIM;
#pragma unroll
  for (int tn = 0; tn < 4; ++tn) {
    const int n = wave * 64 + tn * 16 + col;
    const float bv = bias[n];
#pragma unroll
    for (int tm = 0; tm < 2; ++tm)
#pragma unroll
      for (int r = 0; r < 4; ++r) {
        const int row = tm * 16 + quad * 4 + r;
        acc[tm][tn][r] += bv + resb[(size_t)row * DIM + n];
      }
  }

#pragma unroll
  for (int tm = 0; tm < 2; ++tm)
#pragma unroll
    for (int r = 0; r < 4; ++r) {
      float s = 0.f, q = 0.f;
#pragma unroll
      for (int tn = 0; tn < 4; ++tn) { const float v = acc[tm][tn][r]; s += v; q += v * v; }
      s += __shfl_xor(s, 1); q += __shfl_xor(q, 1);
      s += __shfl_xor(s, 2); q += __shfl_xor(q, 2);
      s += __shfl_xor(s, 4); q += __shfl_xor(q, 4);
      s += __shfl_xor(s, 8); q += __shfl_xor(q, 8);
      if (col == 0) { const int row = tm * 16 + quad * 4 + r; ssum[wave][row] = s; ssq[wave][row] = q; }
    }
  __syncthreads();
  if (tid < 32) {
    const float S = ssum[0][tid] + ssum[1][tid] + ssum[2][tid] + ssum[3][tid];
    const float Q = ssq[0][tid] + ssq[1][tid] + ssq[2][tid] + ssq[3][tid];
    const float mu = S * (1.0f / DIM);
    const float var = Q * (1.0f / DIM) - mu * mu;
    ssum[0][tid] = mu;
    ssq[0][tid] = rsqrtf(var + 1e-5f);
  }
  __syncthreads();

#pragma unroll
  for (int tm = 0; tm < 2; ++tm)
#pragma unroll
    for (int tn = 0; tn < 4; ++tn) {
      const int n = wave * 64 + tn * 16 + col;
      const float g = gs[n], bb2 = gb[n];
#pragma unroll
      for (int r = 0; r < 4; ++r) {
        const int row = tm * 16 + quad * 4 + r;
        const float out = (acc[tm][tn][r] - ssum[0][row]) * ssq[0][row] * g + bb2;
        xoutf[(size_t)(m0 + row) * DIM + n] = out;
        xoutb[(size_t)(m0 + row) * DIM + n] = f2bf(out);
      }
    }
}

// ------------------------------------------------ FF fused: gelu(x@W1+b1)@W2
// + b2 + residual + LN2.  M-tile 32, 1 block/CU.  ALL LDS tiles XOR-granule
// swizzled (phys granule = logical ^ (row&7)), done for free in the DMA
// source address -> every MFMA frag read is 2-way (free) instead of 16-way.
#define HP 1032

__global__ __launch_bounds__(256, 1) void ff_fused(
    const short* __restrict__ xbA, const short* __restrict__ w1T,
    const float* __restrict__ b1, const short* __restrict__ w2T,
    const float* __restrict__ b2, const float* __restrict__ xres,
    const float* __restrict__ gs, const float* __restrict__ gb,
    float* __restrict__ xoutf, short* __restrict__ xoutb)
{
  __shared__ short As[32 * 256];        // 16 KB  [row][32 granules swz]
  __shared__ short Wb[2][64 * 256];     // 2x32 KB (ff1: [64][32g swz], ff2: [256][8g swz])
  __shared__ short Hs[32 * HP];         // 64.5 KB
  __shared__ float ssum[4][32], ssq[4][32];

  const int tid = threadIdx.x;
  const int lane = tid & 63;
  const int wave = tid >> 6;
  const int col = lane & 15, quad = lane >> 4;
  const int m0 = blockIdx.x * 32;

  // stage A (32 rows x 32 granules, source-swizzled) + W1 tile 0
#pragma unroll
  for (int p = 0; p < 4; ++p) {
    int i = p * 256 + tid;
    const int row = i >> 5, gp = i & 31;
    gload16(xbA + (size_t)(m0 + row) * DIM + ((gp ^ (row & 7)) * 8), &As[i * 8]);
  }
#pragma unroll
  for (int p = 0; p < 8; ++p) {
    int i = p * 256 + tid;
    const int row = i >> 5, gp = i & 31;
    gload16(w1T + (size_t)row * DIM + ((gp ^ (row & 7)) * 8), &Wb[0][i * 8]);
  }

  const f32x4 fz = {0.f, 0.f, 0.f, 0.f};
  bf16x8 af1[2][8];

  // ---------------- ff1: h = gelu(x @ W1 + b1) -> Hs
  for (int nt = 0; nt < 16; ++nt) {
    __syncthreads();
    if (nt + 1 < 16) {
#pragma unroll
      for (int p = 0; p < 8; ++p) {
        int i = p * 256 + tid;
        const int row = i >> 5, gp = i & 31;
        gload16(w1T + (size_t)((nt + 1) * 64 + row) * DIM + ((gp ^ (row & 7)) * 8),
                &Wb[(nt + 1) & 1][i * 8]);
      }
    }
    if (nt == 0) {
#pragma unroll
      for (int tm = 0; tm < 2; ++tm) {
        const int row = tm * 16 + col;
#pragma unroll
        for (int kf = 0; kf < 8; ++kf)
          af1[tm][kf] = *(const bf16x8*)&As[(row * 32 + ((kf * 4 + quad) ^ (row & 7))) * 8];
      }
    }
    const short* wb = Wb[nt & 1];
    f32x4 a0 = fz, a1 = fz;
    const int brow = wave * 16 + col;
#pragma unroll
    for (int kf = 0; kf < 8; ++kf) {
      const bf16x8 bfv = *(const bf16x8*)&wb[(brow * 32 + ((kf * 4 + quad) ^ (brow & 7))) * 8];
      a0 = __builtin_amdgcn_mfma_f32_16x16x32_bf16(af1[0][kf], bfv, a0, 0, 0, 0);
      a1 = __builtin_amdgcn_mfma_f32_16x16x32_bf16(af1[1][kf], bfv, a1, 0, 0, 0);
    }
    const int n = nt * 64 + wave * 16 + col;
    const float bv = b1[n];
#pragma unroll
    for (int r = 0; r < 4; ++r) {
      Hs[(quad * 4 + r) * HP + n]      = f2bf(gelu_f(a0[r] + bv));
      Hs[(16 + quad * 4 + r) * HP + n] = f2bf(gelu_f(a1[r] + bv));
    }
  }
  __syncthreads();   // h complete; all W1 reads done

  // stage W2 tile 0 ([256 rows][8 granules], source-swizzled)
#pragma unroll
  for (int p = 0; p < 8; ++p) {
    int i = p * 256 + tid;
    const int row = i >> 3, gp = i & 7;
    gload16(w2T + (size_t)row * FFDIM + ((gp ^ (row & 7)) * 8), &Wb[0][i * 8]);
  }

  // ---------------- ff2: acc = h @ W2
  f32x4 acc[2][4];
#pragma unroll
  for (int i = 0; i < 2; ++i)
#pragma unroll
    for (int j = 0; j < 4; ++j) acc[i][j] = fz;

  for (int kt = 0; kt < 16; ++kt) {
    __syncthreads();
    if (kt + 1 < 16) {
#pragma unroll
      for (int p = 0; p < 8; ++p) {
        int i = p * 256 + tid;
        const int row = i >> 3, gp = i & 7;
        gload16(w2T + (size_t)row * FFDIM + (kt + 1) * 64 + ((gp ^ (row & 7)) * 8),
                &Wb[(kt + 1) & 1][i * 8]);
      }
    }
    const short* wb = Wb[kt & 1];
#pragma unroll
    for (int ks = 0; ks < 2; ++ks) {
      bf16x8 af[2], bfr[4];
#pragma unroll
      for (int tm = 0; tm < 2; ++tm)
        af[tm] = *(const bf16x8*)&Hs[(tm * 16 + col) * HP + kt * 64 + ks * 32 + quad * 8];
#pragma unroll
      for (int tn = 0; tn < 4; ++tn) {
        const int row = wave * 64 + tn * 16 + col;
        bfr[tn] = *(const bf16x8*)&wb[(row * 8 + ((ks * 4 + quad) ^ (row & 7))) * 8];
      }
#pragma unroll
      for (int tm = 0; tm < 2; ++tm)
#pragma unroll
        for (int tn = 0; tn < 4; ++tn)
          acc[tm][tn] = __builtin_amdgcn_mfma_f32_16x16x32_bf16(af[tm], bfr[tn], acc[tm][tn], 0, 0, 0);
    }
  }

  // ---------------- epilogue: bias + residual + LN2
  const float* resb = xres + (size_t)m0 * DIM;
#pragma unroll
  for (int tn = 0; tn < 4; ++tn) {
    const int n = wave * 64 + tn * 16 + col;
    const float bv = b2[n];
#pragma unroll
    for (int tm = 0; tm < 2; ++tm)
#pragma unroll
      for (int r = 0; r < 4; ++r) {
        const int row = tm * 16 + quad * 4 + r;
        acc[tm][tn][r] += bv + resb[(size_t)row * DIM + n];
      }
  }
#pragma unroll
  for (int tm = 0; tm < 2; ++tm)
#pragma unroll
    for (int r = 0; r < 4; ++r) {
      float s = 0.f, q = 0.f;
#pragma unroll
      for (int tn = 0; tn < 4; ++tn) { const float v = acc[tm][tn][r]; s += v; q += v * v; }
      s += __shfl_xor(s, 1); q += __shfl_xor(q, 1);
      s += __shfl_xor(s, 2); q += __shfl_xor(q, 2);
      s += __shfl_xor(s, 4); q += __shfl_xor(q, 4);
      s += __shfl_xor(s, 8); q += __shfl_xor(q, 8);
      if (col == 0) { const int row = tm * 16 + quad * 4 + r; ssum[wave][row] = s; ssq[wave][row] = q; }
    }
  __syncthreads();
  if (tid < 32) {
    const float S = ssum[0][tid] + ssum[1][tid] + ssum[2][tid] + ssum[3][tid];
    const float Q = ssq[0][tid] + ssq[1][tid] + ssq[2][tid] + ssq[3][tid];
    const float mu = S * (1.0f / DIM);
    const float var = Q * (1.0f / DIM) - mu * mu;
    ssum[0][tid] = mu;
    ssq[0][tid] = rsqrtf(var + 1e-5f);
  }
  __syncthreads();
#pragma unroll
  for (int tm = 0; tm < 2; ++tm)
#pragma unroll
    for (int tn = 0; tn < 4; ++tn) {
      const int n = wave * 64 + tn * 16 + col;
      const float g = gs[n], bb2 = gb[n];
#pragma unroll
      for (int r = 0; r < 4; ++r) {
        const int row = tm * 16 + quad * 4 + r;
        const float out = (acc[tm][tn][r] - ssum[0][row]) * ssq[0][row] * g + bb2;
        xoutf[(size_t)(m0 + row) * DIM + n] = out;
        xoutb[(size_t)(m0 + row) * DIM + n] = f2bf(out);
      }
    }
}

// ----------------------------------------------------------------- attention
#define AKT 64
#define KSPL 1024
#define NKT (KSPL / AKT)

__global__ __launch_bounds__(256, 4) void attn_kernel(
    const short* __restrict__ qkv,
    float* __restrict__ Opart, float* __restrict__ lpart)
{
  __shared__ short Kbuf[2][AKT * HDIM];   // [part(4)][key(64)][8]
  __shared__ short Vbuf[2][HDIM * AKT];   // [hd][key-swz]
  __shared__ short Pall[4][32][72];
  __shared__ float Pdiag[4][16];

  const int tid = threadIdx.x;
  const int lane = tid & 63;
  const int wave = tid >> 6;
  const int col = lane & 15, quad = lane >> 4;
  const int bh = blockIdx.y;
  const int b = bh >> 3, h = bh & 7;
  const int hz = blockIdx.z;
  const int q0 = blockIdx.x * 128 + wave * 32;

  short (*P)[72] = Pall[wave];

  const short* qbase = qkv + (size_t)b * TSEQ * 768 + h * HDIM;
  const short* kbase = qbase + 256;
  const short* vcol  = qbase + 512;

  const short* ksrc = kbase + (size_t)(hz * KSPL + (tid & 63)) * 768 + (tid >> 6) * 8;

  const int vhg = (tid & 127) >> 5, vpr = tid & 31;
  const int vva = vpr >> 2, vb8 = (vpr & 3) * 2;
  const short* vsrc = vcol + (size_t)(hz * KSPL + 2 * vpr) * 768 + vhg * 8;
  const bool vact = (tid < 128);

  const bf16x8 qf0 = *(const bf16x8*)(qbase + (size_t)(q0 + col) * 768 + quad * 8);
  const bf16x8 qf1 = *(const bf16x8*)(qbase + (size_t)(q0 + 16 + col) * 768 + quad * 8);

  bf16x8 ones;
#pragma unroll
  for (int i = 0; i < 8; ++i) ones[i] = (short)0x3F80;

  const f32x4 fz = {0.f, 0.f, 0.f, 0.f};
  f32x4 o[2][2] = {{fz, fz}, {fz, fz}};
  f32x4 lacc[2] = {fz, fz};

  gload16(ksrc, &Kbuf[0][tid * 8]);
  bf16x8 vn0, vn1;
  if (vact) {
    const bf16x8 v0 = *(const bf16x8*)vsrc;
    const bf16x8 v1 = *(const bf16x8*)(vsrc + 768);
#pragma unroll
    for (int j = 0; j < 8; ++j) {
      const uint32_t w = (uint32_t)(uint16_t)v0[j] | ((uint32_t)(uint16_t)v1[j] << 16);
      *(uint32_t*)&Vbuf[0][(vhg * 8 + j) * 64 + ((vva ^ j) * 8) + vb8] = w;
    }
    vn0 = *(const bf16x8*)(vsrc + (size_t)AKT * 768);
    vn1 = *(const bf16x8*)(vsrc + (size_t)AKT * 768 + 768);
  }

  int cur = 0;
  for (int t = 0; t < NKT; ++t) {
    __syncthreads();
    if (t + 1 < NKT) {
      gload16(ksrc + (size_t)(t + 1) * AKT * 768, &Kbuf[1 - cur][tid * 8]);
      if (vact) {
#pragma unroll
        for (int j = 0; j < 8; ++j) {
          const uint32_t w = (uint32_t)(uint16_t)vn0[j] | ((uint32_t)(uint16_t)vn1[j] << 16);
          *(uint32_t*)&Vbuf[1 - cur][(vhg * 8 + j) * 64 + ((vva ^ j) * 8) + vb8] = w;
        }
        if (t + 2 < NKT) {
          vn0 = *(const bf16x8*)(vsrc + (size_t)(t + 2) * AKT * 768);
          vn1 = *(const bf16x8*)(vsrc + (size_t)(t + 2) * AKT * 768 + 768);
        }
      }
    }
    const short* kb = Kbuf[cur];
    const short* vb = Vbuf[cur];

#pragma unroll
    for (int st = 0; st < 4; ++st) {
      const bf16x8 kf = *(const bf16x8*)&kb[(quad * 64 + st * 16 + col) * 8];
      const f32x4 s0 = __builtin_amdgcn_mfma_f32_16x16x32_bf16(kf, qf0, fz, 0, 0, 0);
      const f32x4 s1 = __builtin_amdgcn_mfma_f32_16x16x32_bf16(kf, qf1, fz, 0, 0, 0);
      uint2 w0, w1;
      w0.x = pack2bf(fast_exp2(s0[0]), fast_exp2(s0[1]));
      w0.y = pack2bf(fast_exp2(s0[2]), fast_exp2(s0[3]));
      w1.x = pack2bf(fast_exp2(s1[0]), fast_exp2(s1[1]));
      w1.y = pack2bf(fast_exp2(s1[2]), fast_exp2(s1[3]));
      *(uint2*)&P[col][st * 16 + quad * 4] = w0;
      *(uint2*)&P[16 + col][st * 16 + quad * 4] = w1;
    }
    asm volatile("s_waitcnt lgkmcnt(0)" ::: "memory");

#pragma unroll
    for (int kh = 0; kh < 2; ++kh) {
      const bf16x8 pf0 = *(const bf16x8*)&P[col][kh * 32 + quad * 8];
      const bf16x8 pf1 = *(const bf16x8*)&P[16 + col][kh * 32 + quad * 8];
#pragma unroll
      for (int hh = 0; hh < 2; ++hh) {
        const int hd = hh * 16 + col;
        const bf16x8 vf = *(const bf16x8*)&vb[hd * AKT + (((kh * 4 + quad) ^ (hd & 7)) * 8)];
        o[0][hh] = __builtin_amdgcn_mfma_f32_16x16x32_bf16(pf0, vf, o[0][hh], 0, 0, 0);
        o[1][hh] = __builtin_amdgcn_mfma_f32_16x16x32_bf16(pf1, vf, o[1][hh], 0, 0, 0);
      }
      lacc[0] = __builtin_amdgcn_mfma_f32_16x16x32_bf16(pf0, ones, lacc[0], 0, 0, 0);
      lacc[1] = __builtin_amdgcn_mfma_f32_16x16x32_bf16(pf1, ones, lacc[1], 0, 0, 0);
    }
    cur ^= 1;
  }

  if (hz == 1 && blockIdx.x >= SPLITN / 128) {
#pragma unroll
    for (int qsub = 0; qsub < 2; ++qsub) {
      const int qd = q0 + qsub * 16;
      const bf16x8 qf = qsub ? qf1 : qf0;
      const bf16x8 kf = *(const bf16x8*)(kbase + (size_t)(qd + col) * 768 + quad * 8);
      const f32x4 sd = __builtin_amdgcn_mfma_f32_16x16x32_bf16(kf, qf, fz, 0, 0, 0);
      float ps = 0.f;
#pragma unroll
      for (int r = 0; r < 4; ++r)
        if (quad * 4 + r == col) ps = fast_exp2(sd[r]);
      if (quad == (col >> 2)) Pdiag[wave][col] = ps;
      asm volatile("s_waitcnt lgkmcnt(0)" ::: "memory");
      const f32x4 pv = *(const f32x4*)&Pdiag[wave][quad * 4];
#pragma unroll
      for (int r = 0; r < 4; ++r) {
        lacc[qsub][r] += pv[r];
        const size_t vrow = (size_t)(qd + quad * 4 + r) * 768;
#pragma unroll
        for (int hh = 0; hh < 2; ++hh)
          o[qsub][hh][r] += pv[r] * bf2f(vcol[vrow + hh * 16 + col]);
      }
      asm volatile("s_waitcnt lgkmcnt(0)" ::: "memory");
    }
  }

  float* Ob = Opart + (size_t)hz * MROWS * DIM;
  float* lb = lpart + (size_t)hz * 16 * TSEQ + (size_t)bh * TSEQ;
#pragma unroll
  for (int qsub = 0; qsub < 2; ++qsub) {
    const f32x4 la = lacc[qsub];
    const int qq = q0 + qsub * 16 + quad * 4;
    const int rowb = b * TSEQ + qq;
#pragma unroll
    for (int r = 0; r < 4; ++r) {
      if (col == 0) lb[qq + r] = la[r];
#pragma unroll
      for (int hh = 0; hh < 2; ++hh)
        Ob[(size_t)(rowb + r) * DIM + h * HDIM + hh * 16 + col] = o[qsub][hh][r];
    }
  }
}

// ------------------------------------------------------------------ launch
extern "C" void kernel_launch(void* const* d_in, const int* in_sizes, int n_in,
                              void* d_out, int out_size, void* d_ws, size_t ws_size,
                              hipStream_t stream)
{
  const float* rows = (const float*)d_in[0];
  const float* tte  = (const float*)d_in[1];
  const float* Wq = (const float*)d_in[2];  const float* bq = (const float*)d_in[3];
  const float* Wk = (const float*)d_in[4];  const float* bk = (const float*)d_in[5];
  const float* Wv = (const float*)d_in[6];  const float* bv = (const float*)d_in[7];
  const float* Wo = (const float*)d_in[8];  const float* bo = (const float*)d_in[9];
  const float* W1 = (const float*)d_in[10]; const float* b1 = (const float*)d_in[11];
  const float* W2 = (const float*)d_in[12]; const float* b2 = (const float*)d_in[13];
  const float* ln1s = (const float*)d_in[14]; const float* ln1b = (const float*)d_in[15];
  const float* ln2s = (const float*)d_in[16]; const float* ln2b = (const float*)d_in[17];

  char* p = (char*)d_ws;
  float* xf   = (float*)p;  p += (size_t)MROWS * DIM * 4;
  short* xb   = (short*)p;  p += (size_t)MROWS * DIM * 2;
  short* qkv  = (short*)p;  p += (size_t)MROWS * 768 * 2;
  float* Opart = (float*)p; p += (size_t)2 * MROWS * DIM * 4;
  float* lpart = (float*)p; p += (size_t)2 * 16 * TSEQ * 4;
  short* qkvT = (short*)p;  p += (size_t)NLAYER * 768 * DIM * 2;
  short* woT  = (short*)p;  p += (size_t)NLAYER * DIM * DIM * 2;
  short* w1T  = (short*)p;  p += (size_t)NLAYER * FFDIM * DIM * 2;
  short* w2T  = (short*)p;  p += (size_t)NLAYER * DIM * FFDIM * 2;

  prep_w<<<2048, 256, 0, stream>>>(Wq, Wk, Wv, Wo, W1, W2, qkvT, woT, w1T, w2T);
  prep_x<<<MROWS * DIM / 4 / 256, 256, 0, stream>>>(rows, tte, xf, xb);

  for (int l = 0; l < NLAYER; ++l) {
    qkv_gemm<<<dim3(MROWS / 128, 6), 256, 0, stream>>>(
        xb, qkvT + (size_t)l * 768 * DIM, bq + l * DIM, bk + l * DIM, bv + l * DIM, qkv);
    attn_kernel<<<dim3(TSEQ / 128, BATCH * NHEAD, 2), 256, 0, stream>>>(qkv, Opart, lpart);
    wo_ln<<<MROWS / 32, 256, 0, stream>>>(
        Opart, lpart, woT + (size_t)l * DIM * DIM, bo + l * DIM, xf,
        ln1s + l * DIM, ln1b + l * DIM, xf, xb);
    float* xo = (l == NLAYER - 1) ? (float*)d_out : xf;
    ff_fused<<<MROWS / 32, 256, 0, stream>>>(
        xb, w1T + (size_t)l * FFDIM * DIM, b1 + l * FFDIM,
        w2T + (size_t)l * DIM * FFDIM, b2 + l * DIM, xf,
        ln2s + l * DIM, ln2b + l * DIM, xo, xb);
  }
}

// Round 11
// 518.533 us; speedup vs baseline: 1.0521x; 1.0137x over previous
//
#include <hip/hip_runtime.h>
#include <cstdint>
#include <cstddef>

#define TSEQ 4096
#define BATCH 2
#define DIM 256
#define NHEAD 8
#define HDIM 32
#define NLAYER 4
#define FFDIM 1024
#define SPLITN 2048
#define MROWS (BATCH * TSEQ)   // 8192

#define QSCALE 0.2550784545f   // (1/sqrt(HD)) * log2(e), folded into q

typedef __attribute__((ext_vector_type(4))) float f32x4;
typedef __attribute__((ext_vector_type(8))) short bf16x8;

__device__ __forceinline__ short f2bf(float f) {
  union { float f; uint32_t u; } v; v.f = f;
  uint32_t r = v.u + 0x7fffu + ((v.u >> 16) & 1u);
  return (short)(r >> 16);
}

__device__ __forceinline__ float bf2f(short s) {
  union { uint32_t u; float f; } v; v.u = ((uint32_t)(uint16_t)s) << 16;
  return v.f;
}

__device__ __forceinline__ float fast_exp2(float x) {
#if __has_builtin(__builtin_amdgcn_exp2f)
  return __builtin_amdgcn_exp2f(x);
#else
  float r;
  asm volatile("v_exp_f32 %0, %1\n\ts_nop 1" : "=v"(r) : "v"(x));
  return r;
#endif
}

__device__ __forceinline__ uint32_t pack2bf(float a, float b) {
  union { float f; uint32_t u; } ua, ub; ua.f = a; ub.f = b;
  return ((ua.u + 0x8000u) >> 16) | ((ub.u + 0x8000u) & 0xffff0000u);
}

__device__ __forceinline__ float gelu_f(float x) {
  float u = 0.7978845608f * x * (1.0f + 0.044715f * x * x);
  u = fminf(fmaxf(u, -20.f), 20.f);
  float e = fast_exp2(2.885390082f * u);   // exp(2u)
  float t = (e - 1.0f) / (e + 1.0f);
  return 0.5f * x * (1.0f + t);
}

#define AS1 __attribute__((address_space(1)))
#define AS3 __attribute__((address_space(3)))
__device__ __forceinline__ void gload16(const void* g, void* l) {
  __builtin_amdgcn_global_load_lds((AS1 void*)g, (AS3 void*)l, 16, 0, 0);
}

// ---------------------------------------------------------------- weight prep
__global__ __launch_bounds__(256) void prep_w(
    const float* __restrict__ Wq, const float* __restrict__ Wk,
    const float* __restrict__ Wv, const float* __restrict__ Wo,
    const float* __restrict__ W1, const float* __restrict__ W2,
    short* __restrict__ qkvT, short* __restrict__ woT,
    short* __restrict__ w1T, short* __restrict__ w2T)
{
  const int NQKV = NLAYER * 768 * DIM;
  const int NO   = NLAYER * DIM * DIM;
  const int NF   = NLAYER * FFDIM * DIM;
  const int total = NQKV + NO + 2 * NF;
  for (int idx = blockIdx.x * 256 + threadIdx.x; idx < total; idx += gridDim.x * 256) {
    if (idx < NQKV) {                       // qkvT[l][n:768][k:256]
      const int l = idx / (768 * DIM);
      const int rem = idx - l * 768 * DIM;
      const int n = rem >> 8, k = rem & 255;
      const float* src = (n < 256) ? Wq : ((n < 512) ? Wk : Wv);
      qkvT[idx] = f2bf(src[((size_t)l * DIM + k) * DIM + (n & 255)]);
    } else if (idx < NQKV + NO) {           // woT[l][n:256][k:256]
      const int j = idx - NQKV;
      const int l = j >> 16;
      const int rem = j & 65535;
      const int n = rem >> 8, k = rem & 255;
      woT[j] = f2bf(Wo[((size_t)l * DIM + k) * DIM + n]);
    } else if (idx < NQKV + NO + NF) {      // w1T[l][n:1024][k:256]
      const int j = idx - NQKV - NO;
      const int l = j >> 18;
      const int rem = j & 262143;
      const int n = rem >> 8, k = rem & 255;
      w1T[j] = f2bf(W1[((size_t)l * DIM + k) * FFDIM + n]);
    } else {                                // w2T[l][n:256][k:1024]
      const int j = idx - NQKV - NO - NF;
      const int l = j >> 18;
      const int rem = j & 262143;
      const int n = rem >> 10, k = rem & 1023;
      w2T[j] = f2bf(W2[((size_t)l * FFDIM + k) * DIM + n]);
    }
  }
}

// ------------------------------------------------------------------- x prep
__global__ __launch_bounds__(256) void prep_x(
    const float* __restrict__ rows, const float* __restrict__ tte,
    float* __restrict__ xf, short* __restrict__ xb)
{
  const size_t idx = (size_t)blockIdx.x * 256 + threadIdx.x;  // float4 index
  float4 v = ((const float4*)rows)[idx];
  const size_t e = idx * 4;
  const int m = (int)(e >> 8);
  const int d = (int)(e & 255);
  const int t = m & (TSEQ - 1);
  const int bb = m >> 12;
  if (t < SPLITN) {
    const float4 a = ((const float4*)tte)[((size_t)bb * SPLITN + t) * (DIM / 4) + (d >> 2)];
    v.x += a.x; v.y += a.y; v.z += a.z; v.w += a.w;
  }
  ((float4*)xf)[idx] = v;
  short4 pk; pk.x = f2bf(v.x); pk.y = f2bf(v.y); pk.z = f2bf(v.z); pk.w = f2bf(v.w);
  ((short4*)xb)[idx] = pk;
}

// ------------------------------------------------------------------ QKV GEMM
__global__ __launch_bounds__(256, 2) void qkv_gemm(
    const short* __restrict__ A, const short* __restrict__ BT,
    const float* __restrict__ bq, const float* __restrict__ bk,
    const float* __restrict__ bv, short* __restrict__ Cout)
{
  __shared__ short As[128 * 64];
  __shared__ short Bs[128 * 64];
  const int tid = threadIdx.x;
  const int lane = tid & 63;
  const int wave = tid >> 6;
  const int wm = wave & 1, wn = wave >> 1;
  const int col = lane & 15, quad = lane >> 4;

  const short* Ab = A + (size_t)blockIdx.x * 128 * DIM;
  const short* Bb = BT + (size_t)blockIdx.y * 128 * DIM;

  const f32x4 fz = {0.f, 0.f, 0.f, 0.f};
  f32x4 acc[4][4];
#pragma unroll
  for (int i = 0; i < 4; ++i)
#pragma unroll
    for (int j = 0; j < 4; ++j) acc[i][j] = fz;

  for (int k0 = 0; k0 < DIM; k0 += 64) {
#pragma unroll
    for (int p = 0; p < 4; ++p) {
      int i = p * 256 + tid;
      gload16(Ab + (size_t)(i >> 3) * DIM + k0 + (i & 7) * 8, &As[i * 8]);
      gload16(Bb + (size_t)(i >> 3) * DIM + k0 + (i & 7) * 8, &Bs[i * 8]);
    }
    __syncthreads();
#pragma unroll
    for (int ks = 0; ks < 64; ks += 32) {
      bf16x8 af[4], bf[4];
#pragma unroll
      for (int tm = 0; tm < 4; ++tm)
        af[tm] = *(const bf16x8*)&As[(wm * 64 + tm * 16 + col) * 64 + ks + quad * 8];
#pragma unroll
      for (int tn = 0; tn < 4; ++tn)
        bf[tn] = *(const bf16x8*)&Bs[(wn * 64 + tn * 16 + col) * 64 + ks + quad * 8];
#pragma unroll
      for (int tm = 0; tm < 4; ++tm)
#pragma unroll
        for (int tn = 0; tn < 4; ++tn)
          acc[tm][tn] = __builtin_amdgcn_mfma_f32_16x16x32_bf16(af[tm], bf[tn], acc[tm][tn], 0, 0, 0);
    }
    __syncthreads();
  }

#pragma unroll
  for (int tm = 0; tm < 4; ++tm) {
    const int mbase = blockIdx.x * 128 + wm * 64 + tm * 16 + quad * 4;
#pragma unroll
    for (int tn = 0; tn < 4; ++tn) {
      const int n = blockIdx.y * 128 + wn * 64 + tn * 16 + col;
      const float bvv = (n < 256) ? bq[n] : ((n < 512) ? bk[n - 256] : bv[n - 512]);
      const float sc = (n < 256) ? QSCALE : 1.0f;
#pragma unroll
      for (int r = 0; r < 4; ++r)
        Cout[(size_t)(mbase + r) * 768 + n] = f2bf((acc[tm][tn][r] + bvv) * sc);
    }
  }
}

// ------------------------------------------------ Wo GEMM + residual + LN1
__global__ __launch_bounds__(256, 3) void wo_ln(
    const float* __restrict__ Opart, const float* __restrict__ lpart,
    const short* __restrict__ BT, const float* __restrict__ bias,
    const float* __restrict__ xres,
    const float* __restrict__ gs, const float* __restrict__ gb,
    float* __restrict__ xoutf, short* __restrict__ xoutb)
{
  __shared__ short As[32 * 64];
  __shared__ short Bs[256 * 64];
  __shared__ float ssum[4][32], ssq[4][32];
  const int tid = threadIdx.x;
  const int lane = tid & 63;
  const int wave = tid >> 6;
  const int col = lane & 15, quad = lane >> 4;
  const int m0 = blockIdx.x * 32;

  const f32x4 fz = {0.f, 0.f, 0.f, 0.f};
  f32x4 acc[2][4];
#pragma unroll
  for (int i = 0; i < 2; ++i)
#pragma unroll
    for (int j = 0; j < 4; ++j) acc[i][j] = fz;

  const int arow = tid >> 3;
  const int agr  = tid & 7;
  const int grow = m0 + arow;
  const int tt = grow & (TSEQ - 1), bb = grow >> 12;

  for (int k0 = 0; k0 < DIM; k0 += 64) {
    {
      const int head = (k0 >> 5) + (agr >= 4 ? 1 : 0);
      const size_t lidx = (size_t)(bb * 8 + head) * TSEQ + tt;
      const float l = lpart[lidx] + lpart[(size_t)16 * TSEQ + lidx];
      const float li = 1.0f / l;
      const size_t obase = (size_t)grow * DIM + k0 + agr * 8;
      const float4 a0 = *(const float4*)(Opart + obase);
      const float4 a1 = *(const float4*)(Opart + obase + 4);
      const float4 c0 = *(const float4*)(Opart + (size_t)MROWS * DIM + obase);
      const float4 c1 = *(const float4*)(Opart + (size_t)MROWS * DIM + obase + 4);
      uint4 w;
      w.x = pack2bf((a0.x + c0.x) * li, (a0.y + c0.y) * li);
      w.y = pack2bf((a0.z + c0.z) * li, (a0.w + c0.w) * li);
      w.z = pack2bf((a1.x + c1.x) * li, (a1.y + c1.y) * li);
      w.w = pack2bf((a1.z + c1.z) * li, (a1.w + c1.w) * li);
      *(uint4*)&As[arow * 64 + ((agr ^ (arow & 7)) * 8)] = w;
    }
#pragma unroll
    for (int p = 0; p < 8; ++p) {
      int i = p * 256 + tid;
      gload16(BT + (size_t)(i >> 3) * DIM + k0 + (i & 7) * 8, &Bs[i * 8]);
    }
    __syncthreads();
#pragma unroll
    for (int ks = 0; ks < 64; ks += 32) {
      bf16x8 af[2], bfr[4];
#pragma unroll
      for (int tm = 0; tm < 2; ++tm) {
        const int row = tm * 16 + col;
        const int g = (ks >> 3) + quad;
        af[tm] = *(const bf16x8*)&As[row * 64 + ((g ^ (row & 7)) * 8)];
      }
#pragma unroll
      for (int tn = 0; tn < 4; ++tn)
        bfr[tn] = *(const bf16x8*)&Bs[(wave * 64 + tn * 16 + col) * 64 + ks + quad * 8];
#pragma unroll
      for (int tm = 0; tm < 2; ++tm)
#pragma unroll
        for (int tn = 0; tn < 4; ++tn)
          acc[tm][tn] = __builtin_amdgcn_mfma_f32_16x16x32_bf16(af[tm], bfr[tn], acc[tm][tn], 0, 0, 0);
    }
    __syncthreads();
  }

  const float* resb = xres + (size_t)m0 * DIM;
#pragma unroll
  for (int tn = 0; tn < 4; ++tn) {
    const int n = wave * 64 + tn * 16 + col;
    const float bv = bias[n];
#pragma unroll
    for (int tm = 0; tm < 2; ++tm)
#pragma unroll
      for (int r = 0; r < 4; ++r) {
        const int row = tm * 16 + quad * 4 + r;
        acc[tm][tn][r] += bv + resb[(size_t)row * DIM + n];
      }
  }

#pragma unroll
  for (int tm = 0; tm < 2; ++tm)
#pragma unroll
    for (int r = 0; r < 4; ++r) {
      float s = 0.f, q = 0.f;
#pragma unroll
      for (int tn = 0; tn < 4; ++tn) { const float v = acc[tm][tn][r]; s += v; q += v * v; }
      s += __shfl_xor(s, 1); q += __shfl_xor(q, 1);
      s += __shfl_xor(s, 2); q += __shfl_xor(q, 2);
      s += __shfl_xor(s, 4); q += __shfl_xor(q, 4);
      s += __shfl_xor(s, 8); q += __shfl_xor(q, 8);
      if (col == 0) { const int row = tm * 16 + quad * 4 + r; ssum[wave][row] = s; ssq[wave][row] = q; }
    }
  __syncthreads();
  if (tid < 32) {
    const float S = ssum[0][tid] + ssum[1][tid] + ssum[2][tid] + ssum[3][tid];
    const float Q = ssq[0][tid] + ssq[1][tid] + ssq[2][tid] + ssq[3][tid];
    const float mu = S * (1.0f / DIM);
    const float var = Q * (1.0f / DIM) - mu * mu;
    ssum[0][tid] = mu;
    ssq[0][tid] = rsqrtf(var + 1e-5f);
  }
  __syncthreads();

#pragma unroll
  for (int tm = 0; tm < 2; ++tm)
#pragma unroll
    for (int tn = 0; tn < 4; ++tn) {
      const int n = wave * 64 + tn * 16 + col;
      const float g = gs[n], bb2 = gb[n];
#pragma unroll
      for (int r = 0; r < 4; ++r) {
        const int row = tm * 16 + quad * 4 + r;
        const float out = (acc[tm][tn][r] - ssum[0][row]) * ssq[0][row] * g + bb2;
        xoutf[(size_t)(m0 + row) * DIM + n] = out;
        xoutb[(size_t)(m0 + row) * DIM + n] = f2bf(out);
      }
    }
}

// ------------------------------------------------ FF fused v2 (interleaved)
// gelu(x@W1+b1)@W2 + b2 + residual + LN2.  M-tile 32, 1 block/CU.
// 16 chunks of 64 FF cols: ff1 computes h-chunk c into ping-pong LDS while
// ff2 consumes h-chunk c-1; W1/W2 chunks double-buffered DMA (64 KB in
// flight) -> DMA streams continuously behind ONE barrier per chunk.
// x A-frags live in registers (loaded once).  All W tiles XOR-granule
// swizzled in the DMA source; Hb stride 72 is self-conflict-free.
__global__ __launch_bounds__(256, 1) void ff_fused(
    const short* __restrict__ xbA, const short* __restrict__ w1T,
    const float* __restrict__ b1, const short* __restrict__ w2T,
    const float* __restrict__ b2, const float* __restrict__ xres,
    const float* __restrict__ gs, const float* __restrict__ gb,
    float* __restrict__ xoutf, short* __restrict__ xoutb)
{
  __shared__ short Wb1[2][64 * 256];    // ff1 B tiles [ff-local 64][32 g swz]
  __shared__ short Wb2[2][256 * 64];    // ff2 B tiles [n 256][8 g swz]
  __shared__ short Hb[2][32][72];       // h chunk ping-pong [m][k-local 64+pad]
  __shared__ float ssum[4][32], ssq[4][32];

  const int tid = threadIdx.x;
  const int lane = tid & 63;
  const int wave = tid >> 6;
  const int col = lane & 15, quad = lane >> 4;
  const int m0 = blockIdx.x * 32;

  const f32x4 fz = {0.f, 0.f, 0.f, 0.f};

  // x A-fragments -> registers (one-time, ~16 KB/block from L2)
  bf16x8 af1[2][8];
#pragma unroll
  for (int tm = 0; tm < 2; ++tm) {
    const int m = tm * 16 + col;
#pragma unroll
    for (int kf = 0; kf < 8; ++kf)
      af1[tm][kf] = *(const bf16x8*)(xbA + (size_t)(m0 + m) * DIM + kf * 32 + quad * 8);
  }

  // DMA W1 chunk 0
#pragma unroll
  for (int p = 0; p < 8; ++p) {
    int i = p * 256 + tid;
    const int row = i >> 5, gp = i & 31;
    gload16(w1T + (size_t)row * DIM + ((gp ^ (row & 7)) * 8), &Wb1[0][i * 8]);
  }

  f32x4 acc[2][4];
#pragma unroll
  for (int i = 0; i < 2; ++i)
#pragma unroll
    for (int j = 0; j < 4; ++j) acc[i][j] = fz;

  for (int c = 0; c < 16; ++c) {
    __syncthreads();   // drains W1[c] + W2[c-1] DMA; h(c-1) writes visible
    // issue next DMAs
    if (c + 1 < 16) {
#pragma unroll
      for (int p = 0; p < 8; ++p) {
        int i = p * 256 + tid;
        const int row = i >> 5, gp = i & 31;
        gload16(w1T + (size_t)((c + 1) * 64 + row) * DIM + ((gp ^ (row & 7)) * 8),
                &Wb1[(c + 1) & 1][i * 8]);
      }
    }
#pragma unroll
    for (int p = 0; p < 8; ++p) {
      int i = p * 256 + tid;
      const int row = i >> 3, gp = i & 7;
      gload16(w2T + (size_t)row * FFDIM + c * 64 + ((gp ^ (row & 7)) * 8),
              &Wb2[c & 1][i * 8]);
    }

    // ---- ff1: h chunk c -> Hb[c&1]
    {
      const short* wb = Wb1[c & 1];
      const int brow = wave * 16 + col;
      f32x4 a0 = fz, a1 = fz;
#pragma unroll
      for (int kf = 0; kf < 8; ++kf) {
        const bf16x8 bfv = *(const bf16x8*)&wb[(brow * 32 + ((kf * 4 + quad) ^ (brow & 7))) * 8];
        a0 = __builtin_amdgcn_mfma_f32_16x16x32_bf16(af1[0][kf], bfv, a0, 0, 0, 0);
        a1 = __builtin_amdgcn_mfma_f32_16x16x32_bf16(af1[1][kf], bfv, a1, 0, 0, 0);
      }
      const int n = c * 64 + wave * 16 + col;
      const float bv = b1[n];
      const int nl = wave * 16 + col;
#pragma unroll
      for (int r = 0; r < 4; ++r) {
        Hb[c & 1][quad * 4 + r][nl]      = f2bf(gelu_f(a0[r] + bv));
        Hb[c & 1][16 + quad * 4 + r][nl] = f2bf(gelu_f(a1[r] + bv));
      }
    }

    // ---- ff2: consume h chunk c-1 (barrier already made it visible)
    if (c > 0) {
      const int cp = c - 1;
      const short* wb = Wb2[cp & 1];
#pragma unroll
      for (int kh = 0; kh < 2; ++kh) {
        bf16x8 af[2], bfr[4];
#pragma unroll
        for (int tm = 0; tm < 2; ++tm)
          af[tm] = *(const bf16x8*)&Hb[cp & 1][tm * 16 + col][(kh * 4 + quad) * 8];
#pragma unroll
        for (int tn = 0; tn < 4; ++tn) {
          const int row = wave * 64 + tn * 16 + col;
          bfr[tn] = *(const bf16x8*)&wb[(row * 8 + ((kh * 4 + quad) ^ (row & 7))) * 8];
        }
#pragma unroll
        for (int tm = 0; tm < 2; ++tm)
#pragma unroll
          for (int tn = 0; tn < 4; ++tn)
            acc[tm][tn] = __builtin_amdgcn_mfma_f32_16x16x32_bf16(af[tm], bfr[tn], acc[tm][tn], 0, 0, 0);
      }
    }
  }

  // final chunk (c=15) of ff2
  __syncthreads();
  {
    const short* wb = Wb2[15 & 1];
#pragma unroll
    for (int kh = 0; kh < 2; ++kh) {
      bf16x8 af[2], bfr[4];
#pragma unroll
      for (int tm = 0; tm < 2; ++tm)
        af[tm] = *(const bf16x8*)&Hb[1][tm * 16 + col][(kh * 4 + quad) * 8];
#pragma unroll
      for (int tn = 0; tn < 4; ++tn) {
        const int row = wave * 64 + tn * 16 + col;
        bfr[tn] = *(const bf16x8*)&wb[(row * 8 + ((kh * 4 + quad) ^ (row & 7))) * 8];
      }
#pragma unroll
      for (int tm = 0; tm < 2; ++tm)
#pragma unroll
        for (int tn = 0; tn < 4; ++tn)
          acc[tm][tn] = __builtin_amdgcn_mfma_f32_16x16x32_bf16(af[tm], bfr[tn], acc[tm][tn], 0, 0, 0);
    }
  }

  // ---------------- epilogue: bias + residual + LN2
  const float* resb = xres + (size_t)m0 * DIM;
#pragma unroll
  for (int tn = 0; tn < 4; ++tn) {
    const int n = wave * 64 + tn * 16 + col;
    const float bv = b2[n];
#pragma unroll
    for (int tm = 0; tm < 2; ++tm)
#pragma unroll
      for (int r = 0; r < 4; ++r) {
        const int row = tm * 16 + quad * 4 + r;
        acc[tm][tn][r] += bv + resb[(size_t)row * DIM + n];
      }
  }
#pragma unroll
  for (int tm = 0; tm < 2; ++tm)
#pragma unroll
    for (int r = 0; r < 4; ++r) {
      float s = 0.f, q = 0.f;
#pragma unroll
      for (int tn = 0; tn < 4; ++tn) { const float v = acc[tm][tn][r]; s += v; q += v * v; }
      s += __shfl_xor(s, 1); q += __shfl_xor(q, 1);
      s += __shfl_xor(s, 2); q += __shfl_xor(q, 2);
      s += __shfl_xor(s, 4); q += __shfl_xor(q, 4);
      s += __shfl_xor(s, 8); q += __shfl_xor(q, 8);
      if (col == 0) { const int row = tm * 16 + quad * 4 + r; ssum[wave][row] = s; ssq[wave][row] = q; }
    }
  __syncthreads();
  if (tid < 32) {
    const float S = ssum[0][tid] + ssum[1][tid] + ssum[2][tid] + ssum[3][tid];
    const float Q = ssq[0][tid] + ssq[1][tid] + ssq[2][tid] + ssq[3][tid];
    const float mu = S * (1.0f / DIM);
    const float var = Q * (1.0f / DIM) - mu * mu;
    ssum[0][tid] = mu;
    ssq[0][tid] = rsqrtf(var + 1e-5f);
  }
  __syncthreads();
#pragma unroll
  for (int tm = 0; tm < 2; ++tm)
#pragma unroll
    for (int tn = 0; tn < 4; ++tn) {
      const int n = wave * 64 + tn * 16 + col;
      const float g = gs[n], bb2 = gb[n];
#pragma unroll
      for (int r = 0; r < 4; ++r) {
        const int row = tm * 16 + quad * 4 + r;
        const float out = (acc[tm][tn][r] - ssum[0][row]) * ssq[0][row] * g + bb2;
        xoutf[(size_t)(m0 + row) * DIM + n] = out;
        xoutb[(size_t)(m0 + row) * DIM + n] = f2bf(out);
      }
    }
}

// ----------------------------------------------------------------- attention
#define AKT 64
#define KSPL 1024
#define NKT (KSPL / AKT)

__global__ __launch_bounds__(256, 4) void attn_kernel(
    const short* __restrict__ qkv,
    float* __restrict__ Opart, float* __restrict__ lpart)
{
  __shared__ short Kbuf[2][AKT * HDIM];   // [part(4)][key(64)][8]
  __shared__ short Vbuf[2][HDIM * AKT];   // [hd][key-swz]
  __shared__ short Pall[4][32][72];
  __shared__ float Pdiag[4][16];

  const int tid = threadIdx.x;
  const int lane = tid & 63;
  const int wave = tid >> 6;
  const int col = lane & 15, quad = lane >> 4;
  const int bh = blockIdx.y;
  const int b = bh >> 3, h = bh & 7;
  const int hz = blockIdx.z;
  const int q0 = blockIdx.x * 128 + wave * 32;

  short (*P)[72] = Pall[wave];

  const short* qbase = qkv + (size_t)b * TSEQ * 768 + h * HDIM;
  const short* kbase = qbase + 256;
  const short* vcol  = qbase + 512;

  const short* ksrc = kbase + (size_t)(hz * KSPL + (tid & 63)) * 768 + (tid >> 6) * 8;

  const int vhg = (tid & 127) >> 5, vpr = tid & 31;
  const int vva = vpr >> 2, vb8 = (vpr & 3) * 2;
  const short* vsrc = vcol + (size_t)(hz * KSPL + 2 * vpr) * 768 + vhg * 8;
  const bool vact = (tid < 128);

  const bf16x8 qf0 = *(const bf16x8*)(qbase + (size_t)(q0 + col) * 768 + quad * 8);
  const bf16x8 qf1 = *(const bf16x8*)(qbase + (size_t)(q0 + 16 + col) * 768 + quad * 8);

  bf16x8 ones;
#pragma unroll
  for (int i = 0; i < 8; ++i) ones[i] = (short)0x3F80;

  const f32x4 fz = {0.f, 0.f, 0.f, 0.f};
  f32x4 o[2][2] = {{fz, fz}, {fz, fz}};
  f32x4 lacc[2] = {fz, fz};

  gload16(ksrc, &Kbuf[0][tid * 8]);
  bf16x8 vn0, vn1;
  if (vact) {
    const bf16x8 v0 = *(const bf16x8*)vsrc;
    const bf16x8 v1 = *(const bf16x8*)(vsrc + 768);
#pragma unroll
    for (int j = 0; j < 8; ++j) {
      const uint32_t w = (uint32_t)(uint16_t)v0[j] | ((uint32_t)(uint16_t)v1[j] << 16);
      *(uint32_t*)&Vbuf[0][(vhg * 8 + j) * 64 + ((vva ^ j) * 8) + vb8] = w;
    }
    vn0 = *(const bf16x8*)(vsrc + (size_t)AKT * 768);
    vn1 = *(const bf16x8*)(vsrc + (size_t)AKT * 768 + 768);
  }

  int cur = 0;
  for (int t = 0; t < NKT; ++t) {
    __syncthreads();
    if (t + 1 < NKT) {
      gload16(ksrc + (size_t)(t + 1) * AKT * 768, &Kbuf[1 - cur][tid * 8]);
      if (vact) {
#pragma unroll
        for (int j = 0; j < 8; ++j) {
          const uint32_t w = (uint32_t)(uint16_t)vn0[j] | ((uint32_t)(uint16_t)vn1[j] << 16);
          *(uint32_t*)&Vbuf[1 - cur][(vhg * 8 + j) * 64 + ((vva ^ j) * 8) + vb8] = w;
        }
        if (t + 2 < NKT) {
          vn0 = *(const bf16x8*)(vsrc + (size_t)(t + 2) * AKT * 768);
          vn1 = *(const bf16x8*)(vsrc + (size_t)(t + 2) * AKT * 768 + 768);
        }
      }
    }
    const short* kb = Kbuf[cur];
    const short* vb = Vbuf[cur];

#pragma unroll
    for (int st = 0; st < 4; ++st) {
      const bf16x8 kf = *(const bf16x8*)&kb[(quad * 64 + st * 16 + col) * 8];
      const f32x4 s0 = __builtin_amdgcn_mfma_f32_16x16x32_bf16(kf, qf0, fz, 0, 0, 0);
      const f32x4 s1 = __builtin_amdgcn_mfma_f32_16x16x32_bf16(kf, qf1, fz, 0, 0, 0);
      uint2 w0, w1;
      w0.x = pack2bf(fast_exp2(s0[0]), fast_exp2(s0[1]));
      w0.y = pack2bf(fast_exp2(s0[2]), fast_exp2(s0[3]));
      w1.x = pack2bf(fast_exp2(s1[0]), fast_exp2(s1[1]));
      w1.y = pack2bf(fast_exp2(s1[2]), fast_exp2(s1[3]));
      *(uint2*)&P[col][st * 16 + quad * 4] = w0;
      *(uint2*)&P[16 + col][st * 16 + quad * 4] = w1;
    }
    asm volatile("s_waitcnt lgkmcnt(0)" ::: "memory");

#pragma unroll
    for (int kh = 0; kh < 2; ++kh) {
      const bf16x8 pf0 = *(const bf16x8*)&P[col][kh * 32 + quad * 8];
      const bf16x8 pf1 = *(const bf16x8*)&P[16 + col][kh * 32 + quad * 8];
#pragma unroll
      for (int hh = 0; hh < 2; ++hh) {
        const int hd = hh * 16 + col;
        const bf16x8 vf = *(const bf16x8*)&vb[hd * AKT + (((kh * 4 + quad) ^ (hd & 7)) * 8)];
        o[0][hh] = __builtin_amdgcn_mfma_f32_16x16x32_bf16(pf0, vf, o[0][hh], 0, 0, 0);
        o[1][hh] = __builtin_amdgcn_mfma_f32_16x16x32_bf16(pf1, vf, o[1][hh], 0, 0, 0);
      }
      lacc[0] = __builtin_amdgcn_mfma_f32_16x16x32_bf16(pf0, ones, lacc[0], 0, 0, 0);
      lacc[1] = __builtin_amdgcn_mfma_f32_16x16x32_bf16(pf1, ones, lacc[1], 0, 0, 0);
    }
    cur ^= 1;
  }

  if (hz == 1 && blockIdx.x >= SPLITN / 128) {
#pragma unroll
    for (int qsub = 0; qsub < 2; ++qsub) {
      const int qd = q0 + qsub * 16;
      const bf16x8 qf = qsub ? qf1 : qf0;
      const bf16x8 kf = *(const bf16x8*)(kbase + (size_t)(qd + col) * 768 + quad * 8);
      const f32x4 sd = __builtin_amdgcn_mfma_f32_16x16x32_bf16(kf, qf, fz, 0, 0, 0);
      float ps = 0.f;
#pragma unroll
      for (int r = 0; r < 4; ++r)
        if (quad * 4 + r == col) ps = fast_exp2(sd[r]);
      if (quad == (col >> 2)) Pdiag[wave][col] = ps;
      asm volatile("s_waitcnt lgkmcnt(0)" ::: "memory");
      const f32x4 pv = *(const f32x4*)&Pdiag[wave][quad * 4];
#pragma unroll
      for (int r = 0; r < 4; ++r) {
        lacc[qsub][r] += pv[r];
        const size_t vrow = (size_t)(qd + quad * 4 + r) * 768;
#pragma unroll
        for (int hh = 0; hh < 2; ++hh)
          o[qsub][hh][r] += pv[r] * bf2f(vcol[vrow + hh * 16 + col]);
      }
      asm volatile("s_waitcnt lgkmcnt(0)" ::: "memory");
    }
  }

  float* Ob = Opart + (size_t)hz * MROWS * DIM;
  float* lb = lpart + (size_t)hz * 16 * TSEQ + (size_t)bh * TSEQ;
#pragma unroll
  for (int qsub = 0; qsub < 2; ++qsub) {
    const f32x4 la = lacc[qsub];
    const int qq = q0 + qsub * 16 + quad * 4;
    const int rowb = b * TSEQ + qq;
#pragma unroll
    for (int r = 0; r < 4; ++r) {
      if (col == 0) lb[qq + r] = la[r];
#pragma unroll
      for (int hh = 0; hh < 2; ++hh)
        Ob[(size_t)(rowb + r) * DIM + h * HDIM + hh * 16 + col] = o[qsub][hh][r];
    }
  }
}

// ------------------------------------------------------------------ launch
extern "C" void kernel_launch(void* const* d_in, const int* in_sizes, int n_in,
                              void* d_out, int out_size, void* d_ws, size_t ws_size,
                              hipStream_t stream)
{
  const float* rows = (const float*)d_in[0];
  const float* tte  = (const float*)d_in[1];
  const float* Wq = (const float*)d_in[2];  const float* bq = (const float*)d_in[3];
  const float* Wk = (const float*)d_in[4];  const float* bk = (const float*)d_in[5];
  const float* Wv = (const float*)d_in[6];  const float* bv = (const float*)d_in[7];
  const float* Wo = (const float*)d_in[8];  const float* bo = (const float*)d_in[9];
  const float* W1 = (const float*)d_in[10]; const float* b1 = (const float*)d_in[11];
  const float* W2 = (const float*)d_in[12]; const float* b2 = (const float*)d_in[13];
  const float* ln1s = (const float*)d_in[14]; const float* ln1b = (const float*)d_in[15];
  const float* ln2s = (const float*)d_in[16]; const float* ln2b = (const float*)d_in[17];

  char* p = (char*)d_ws;
  float* xf   = (float*)p;  p += (size_t)MROWS * DIM * 4;
  short* xb   = (short*)p;  p += (size_t)MROWS * DIM * 2;
  short* qkv  = (short*)p;  p += (size_t)MROWS * 768 * 2;
  float* Opart = (float*)p; p += (size_t)2 * MROWS * DIM * 4;
  float* lpart = (float*)p; p += (size_t)2 * 16 * TSEQ * 4;
  short* qkvT = (short*)p;  p += (size_t)NLAYER * 768 * DIM * 2;
  short* woT  = (short*)p;  p += (size_t)NLAYER * DIM * DIM * 2;
  short* w1T  = (short*)p;  p += (size_t)NLAYER * FFDIM * DIM * 2;
  short* w2T  = (short*)p;  p += (size_t)NLAYER * DIM * FFDIM * 2;

  prep_w<<<2048, 256, 0, stream>>>(Wq, Wk, Wv, Wo, W1, W2, qkvT, woT, w1T, w2T);
  prep_x<<<MROWS * DIM / 4 / 256, 256, 0, stream>>>(rows, tte, xf, xb);

  for (int l = 0; l < NLAYER; ++l) {
    qkv_gemm<<<dim3(MROWS / 128, 6), 256, 0, stream>>>(
        xb, qkvT + (size_t)l * 768 * DIM, bq + l * DIM, bk + l * DIM, bv + l * DIM, qkv);
    attn_kernel<<<dim3(TSEQ / 128, BATCH * NHEAD, 2), 256, 0, stream>>>(qkv, Opart, lpart);
    wo_ln<<<MROWS / 32, 256, 0, stream>>>(
        Opart, lpart, woT + (size_t)l * DIM * DIM, bo + l * DIM, xf,
        ln1s + l * DIM, ln1b + l * DIM, xf, xb);
    float* xo = (l == NLAYER - 1) ? (float*)d_out : xf;
    ff_fused<<<MROWS / 32, 256, 0, stream>>>(
        xb, w1T + (size_t)l * FFDIM * DIM, b1 + l * FFDIM,
        w2T + (size_t)l * DIM * FFDIM, b2 + l * DIM, xf,
        ln2s + l * DIM, ln2b + l * DIM, xo, xb);
  }
}